// Round 3
// baseline (315.960 us; speedup 1.0000x reference)
//
#include <hip/hip_runtime.h>
#include <hip/hip_bf16.h>
#include <stdint.h>

#define N_PTS 100000
#define INC 128
#define NSLOT 27
#define CAPP 8192                 // pairs per slot-bucket (expected ~620)
#define SCAP 64                   // LDS staging cap per slot per block

typedef float f32x4 __attribute__((ext_vector_type(4)));
typedef short bf16x8 __attribute__((ext_vector_type(8)));

// ---------------- workspace layout --------------------------------------
static const size_t OFF_WP   = 0;                                        // 27 slots frag-packed bf16
static const size_t SZ_WP    = (size_t)NSLOT * INC * INC * 2;
static const size_t OFF_WPRE = (OFF_WP + SZ_WP + 255) & ~(size_t)255;    // w_pre frag-packed bf16
static const size_t SZ_WPRE  = (size_t)INC * INC * 2;
static const size_t OFF_FIN  = (OFF_WPRE + SZ_WPRE + 255) & ~(size_t)255; // F_input bf16
static const size_t SZ_FIN   = (size_t)N_PTS * INC * 2;
static const size_t OFF_LOC  = (OFF_FIN + SZ_FIN + 255) & ~(size_t)255;   // local accum f32
static const size_t SZ_LOC   = (size_t)N_PTS * INC * 4;
static const size_t OFF_AUX  = (OFF_LOC + SZ_LOC + 255) & ~(size_t)255;   // aux rows f32 (by aux_idx)
static const size_t SZ_AUX   = (size_t)N_PTS * 3 * INC * 4;
static const size_t OFF_CNT  = (OFF_AUX + SZ_AUX + 255) & ~(size_t)255;   // 26 bucket counters + [26]=ndl count
static const size_t SZ_CNT   = 128;
static const size_t OFF_DST  = (OFF_CNT + SZ_CNT + 255) & ~(size_t)255;
static const size_t SZ_DST   = (size_t)26 * CAPP * 4;
static const size_t OFF_SRC  = (OFF_DST + SZ_DST + 255) & ~(size_t)255;
static const size_t SZ_SRC   = (size_t)26 * CAPP * 4;
static const size_t OFF_FLG  = (OFF_SRC + SZ_SRC + 255) & ~(size_t)255;   // per-point flags u8
static const size_t SZ_FLG   = (size_t)N_PTS;
static const size_t OFF_NDL  = (OFF_FLG + SZ_FLG + 255) & ~(size_t)255;   // needs-final point list
static const size_t SZ_NDL   = (size_t)N_PTS * 4;                          // total ~234.5 MB

__device__ __forceinline__ float compute_pos3(float w0, float w1, float w2, float a,
                                              float cx, float cy, float cz) {
    return (cx * w0 + cy * w1 + cz * w2) * a;
}

// load 8 consecutive f32 and round to a bf16x8 MFMA fragment
__device__ __forceinline__ bf16x8 ld_cvt8(const float* __restrict__ p) {
    const float4 u = *(const float4*)p;
    const float4 v = *(const float4*)(p + 4);
    bf16x8 r;
    __hip_bfloat16* h = (__hip_bfloat16*)&r;
    h[0] = __float2bfloat16(u.x); h[1] = __float2bfloat16(u.y);
    h[2] = __float2bfloat16(u.z); h[3] = __float2bfloat16(u.w);
    h[4] = __float2bfloat16(v.x); h[5] = __float2bfloat16(v.y);
    h[6] = __float2bfloat16(v.z); h[7] = __float2bfloat16(v.w);
    return r;
}

// ---------------- K_prep: pack weights (coalesced source reads) -------------
__global__ __launch_bounds__(256) void k_prep(
        const float* __restrict__ w_pre, const float* __restrict__ w_conv,
        __hip_bfloat16* __restrict__ Wp, __hip_bfloat16* __restrict__ Wpre) {
    int i = blockIdx.x * 256 + threadIdx.x;
    if (i < 16384) {                        // w_pre: B[n=d][k=c] = w_pre[d*128+c]
        int d = i >> 7, c = i & 127;
        int j = ((c >> 5) << 12) | ((d >> 4) << 9)
              | (((((c >> 3) & 3) << 4) + (d & 15)) << 3) | (c & 7);
        Wpre[j] = __float2bfloat16(w_pre[i]);
    } else if (i < 16384 + NSLOT * 16384) { // w_conv: B[n=d][k=c] = w_conv[slot][c][d]
        int t = i - 16384;
        int slot = t >> 14, rem = t & 16383;
        int c = rem >> 7, d = rem & 127;
        int j = (slot << 14) | ((c >> 5) << 12) | ((d >> 4) << 9)
              | (((((c >> 3) & 3) << 4) + (d & 15)) << 3) | (c & 7);
        Wp[j] = __float2bfloat16(w_conv[t]);
    }
}

// ---------------- K_scan: pair compaction + flags + needs-final list --------
__global__ __launch_bounds__(256) void k_scan(
        const int* __restrict__ nbr_idx, const float* __restrict__ counts_v,
        const int* __restrict__ aux_idx, float* __restrict__ aux,
        int* __restrict__ cnt, int* __restrict__ dst, int* __restrict__ src,
        unsigned char* __restrict__ flg, int* __restrict__ ndl) {
    __shared__ int s_cnt[26], s_base[26];
    __shared__ int s_dst[26][SCAP], s_src[26][SCAP];

    const int tid = threadIdx.x;
    const int lane = tid & 63;
    const int p = blockIdx.x * 256 + tid;
    const bool vp = p < N_PTS;

    if (tid < 26) s_cnt[tid] = 0;
    __syncthreads();

    float cv = vp ? counts_v[p] : 0.f;
    bool multi = cv > 1.5f;
    if (multi) {                             // zero this point's cell aux row (idempotent)
        float4* row = (float4*)(aux + (size_t)aux_idx[p] * (3 * INC));
#pragma unroll
        for (int i = 0; i < (3 * INC) / 4; ++i) row[i] = make_float4(0.f, 0.f, 0.f, 0.f);
    }

    const int* nb = nbr_idx + (size_t)p * NSLOT;
    bool hn = false;
#pragma unroll 1
    for (int k = 0; k < NSLOT; ++k) {
        if (k == 13) continue;               // self handled densely
        int m = vp ? nb[k] : N_PTS;
        if (m < N_PTS) {
            hn = true;
            int b = k < 13 ? k : k - 1;      // 0..25
            int li = atomicAdd(&s_cnt[b], 1);
            if (li < SCAP) { s_dst[b][li] = p; s_src[b][li] = m; }
            else {
                int gi = atomicAdd(&cnt[b], 1);
                if (gi < CAPP) { dst[b * CAPP + gi] = p; src[b * CAPP + gi] = m; }
            }
        }
    }

    // flags: bit0 = needs k_final (multi or has occupied neighbor), bit1 = multi
    bool nd = vp && (hn || multi);
    if (vp) flg[p] = (unsigned char)((nd ? 1 : 0) | (multi ? 2 : 0));
    unsigned long long mb = __ballot(nd);
    int basew = 0;
    if (lane == 0 && mb) basew = atomicAdd(&cnt[26], __popcll(mb));
    basew = __shfl(basew, 0);
    if (nd) ndl[basew + __popcll(mb & ((1ull << lane) - 1))] = p;

    __syncthreads();

    if (tid < 26) {
        int n = s_cnt[tid]; if (n > SCAP) n = SCAP;
        s_base[tid] = n > 0 ? atomicAdd(&cnt[tid], n) : 0;
        s_cnt[tid] = n;
    }
    __syncthreads();

    for (int b = tid >> 3; b < 26; b += 32) {
        int n = s_cnt[b], base = s_base[b];
        for (int e = tid & 7; e < n; e += 8) {
            int gi = base + e;
            if (gi < CAPP) { dst[b * CAPP + gi] = s_dst[b][e]; src[b * CAPP + gi] = s_src[b][e]; }
        }
    }
}

// ---------------- K_gemm: pre_mix + self-conv GEMMs, fused final for done rows
// Restructured for TLP: 16 rows per wave (was 32) -> 6250 waves = 24.4/CU.
// A-fragments (bf16) held in registers across BOTH passes -> F read ONCE.
// Block = 4 waves x 16 rows = 64 rows; grid = 1563. LDS 20.5 KB -> 7 blocks/CU.
__global__ __launch_bounds__(256, 6) void k_gemm(
        const float* __restrict__ F, const __hip_bfloat16* __restrict__ Wpre,
        const __hip_bfloat16* __restrict__ Wp, const int* __restrict__ coords,
        const int* __restrict__ aux_idx, const unsigned char* __restrict__ flg,
        const float* __restrict__ w_pos, const float* __restrict__ alpha,
        const float* __restrict__ g_pre, const float* __restrict__ b_pre,
        const float* __restrict__ g_local, const float* __restrict__ b_local,
        const float* __restrict__ g_norm, const float* __restrict__ b_norm,
        __hip_bfloat16* __restrict__ F_input, float* __restrict__ loc,
        float* __restrict__ aux, float* __restrict__ outp) {
    __shared__ char s_buf[4][4352];            // per-wave, time-shared bf16[16][136] / f32[16][68]
    __shared__ float s_gp[INC], s_bp[INC], s_gl[INC], s_bl[INC], s_gn[INC], s_bn[INC];

    const int tid = threadIdx.x, w = tid >> 6, lane = tid & 63;
    const int q = lane >> 4, l15 = lane & 15;
    const int p0 = blockIdx.x * 64;

    if (tid < INC) {
        s_gp[tid] = g_pre[tid];   s_bp[tid] = b_pre[tid];
        s_gl[tid] = g_local[tid]; s_bl[tid] = b_local[tid];
        s_gn[tid] = g_norm[tid];  s_bn[tid] = b_norm[tid];
    }
    __syncthreads();

    int grow = p0 + (w << 4) + l15;
    if (grow >= N_PTS) grow = N_PTS - 1;      // clamp; stores guarded

    const float* A = F + (size_t)grow * INC + q * 8;

    __hip_bfloat16* s_bf = (__hip_bfloat16*)s_buf[w];   // [16][136] bf16 phase
    float*          s_f  = (float*)s_buf[w];            // [16][68] f32 phase (after)

    // A fragments: load + convert ONCE, reuse in both passes
    bf16x8 a[4];
#pragma unroll
    for (int ks = 0; ks < 4; ++ks) a[ks] = ld_cvt8(A + ks * 32);

    // ================= pass P: pre_mix GEMM =================
    {
        const bf16x8* Bp = (const bf16x8*)Wpre;
        f32x4 acc[8];
#pragma unroll
        for (int j = 0; j < 8; ++j) acc[j] = (f32x4){0.f, 0.f, 0.f, 0.f};
#pragma unroll
        for (int ks = 0; ks < 4; ++ks) {
#pragma unroll
            for (int j = 0; j < 8; ++j) {
                bf16x8 b = Bp[(ks * 8 + j) * 64 + lane];
                acc[j] = __builtin_amdgcn_mfma_f32_16x16x32_bf16(a[ks], b, acc[j], 0, 0, 0);
            }
        }
        // LN_pre epilogue -> bf16 LDS + aux atomics
#pragma unroll
        for (int r = 0; r < 4; ++r) {
            int ri = (q << 2) + r;
            int p = p0 + (w << 4) + ri;
            float vj[8], s = 0.f, ss = 0.f;
#pragma unroll
            for (int j = 0; j < 8; ++j) { float v = acc[j][r]; vj[j] = v; s += v; ss += v * v; }
#pragma unroll
            for (int m = 1; m < 16; m <<= 1) { s += __shfl_xor(s, m); ss += __shfl_xor(ss, m); }
            float mean = s * (1.f / 128.f);
            float rstd = rsqrtf(ss * (1.f / 128.f) - mean * mean + 1e-6f);
            bool multi = p < N_PTS && (flg[p] & 2);
            float cx = 0.f, cy = 0.f, cz = 0.f;
            float* auxp = aux;
            if (multi) {
                cx = (float)coords[p * 3 + 0]; cy = (float)coords[p * 3 + 1];
                cz = (float)coords[p * 3 + 2];
                auxp = aux + (size_t)aux_idx[p] * (3 * INC);
            }
#pragma unroll
            for (int j = 0; j < 8; ++j) {
                int c = (j << 4) + l15;
                float fi = (vj[j] - mean) * rstd * s_gp[c] + s_bp[c];
                __hip_bfloat16 fb = __float2bfloat16(fi);
                s_bf[ri * 136 + c] = fb;
                if (multi) {
                    float fr = __bfloat162float(fb);
                    const float* wp = w_pos + c * 3;
                    float ps = compute_pos3(wp[0], wp[1], wp[2], alpha[c], cx, cy, cz);
                    float sn = __sinf(ps), cs = __cosf(ps);
                    atomicAdd(auxp + c,           fr * cs);
                    atomicAdd(auxp + INC + c,     fr * sn);
                    atomicAdd(auxp + 2 * INC + c, fr * ps);
                }
            }
        }
        // F_input store only for needs-final rows
#pragma unroll
        for (int t = 0; t < 4; ++t) {
            int row = (t << 2) + q;
            int p = p0 + (w << 4) + row;
            if (p < N_PTS && (flg[p] & 1)) {
                bf16x8 v = *(const bf16x8*)&s_bf[row * 136 + l15 * 8];
                *(bf16x8*)(F_input + (size_t)p * INC + l15 * 8) = v;
            }
        }
    }

    // ================= pass L: self-slot conv GEMM + fused final ============
    {
        const bf16x8* Bp = (const bf16x8*)Wp + (size_t)13 * 2048;   // self slot
        f32x4 acc[8];
#pragma unroll
        for (int j = 0; j < 8; ++j) acc[j] = (f32x4){0.f, 0.f, 0.f, 0.f};
#pragma unroll
        for (int ks = 0; ks < 4; ++ks) {
#pragma unroll
            for (int j = 0; j < 8; ++j) {
                bf16x8 b = Bp[(ks * 8 + j) * 64 + lane];
                acc[j] = __builtin_amdgcn_mfma_f32_16x16x32_bf16(a[ks], b, acc[j], 0, 0, 0);
            }
        }
        // fused epilogue: done rows -> out = relu(LN(F_input) + LN(local));
        //                 needs-final rows -> raw local conv into loc
        // NOTE: all s_bf (bf16) reads happen here, BEFORE staging reuses the bytes.
        float ov[8][4];
#pragma unroll
        for (int r = 0; r < 4; ++r) {
            int ri = (q << 2) + r;
            int p = p0 + (w << 4) + ri;
            int fl = (p < N_PTS) ? flg[p] : 1;
            float lv[8], sL = 0.f, ssL = 0.f;
#pragma unroll
            for (int j = 0; j < 8; ++j) { float v = acc[j][r]; lv[j] = v; sL += v; ssL += v * v; }
            float fj[8], sN = 0.f, ssN = 0.f;
#pragma unroll
            for (int j = 0; j < 8; ++j) {
                float v = __bfloat162float(s_bf[ri * 136 + (j << 4) + l15]);
                fj[j] = v; sN += v; ssN += v * v;
            }
#pragma unroll
            for (int m = 1; m < 16; m <<= 1) {
                sL += __shfl_xor(sL, m); ssL += __shfl_xor(ssL, m);
                sN += __shfl_xor(sN, m); ssN += __shfl_xor(ssN, m);
            }
            float meanL = sL * (1.f / 128.f);
            float rstdL = rsqrtf(ssL * (1.f / 128.f) - meanL * meanL + 1e-6f);
            float meanN = sN * (1.f / 128.f);
            float rstdN = rsqrtf(ssN * (1.f / 128.f) - meanN * meanN + 1e-6f);
#pragma unroll
            for (int j = 0; j < 8; ++j) {
                int c = (j << 4) + l15;
                float nn = (fj[j] - meanN) * rstdN * s_gn[c] + s_bn[c];
                float ll = (lv[j] - meanL) * rstdL * s_gl[c] + s_bl[c];
                float o = nn + ll; o = o > 0.f ? o : 0.f;
                ov[j][r] = (fl & 1) ? lv[j] : o;
            }
        }
        // stage + coalesced store; per-row destination = needs-final ? loc : out
        // s_f aliases s_buf[w] -- bf16 contents are dead from here on.
#pragma unroll
        for (int h = 0; h < 2; ++h) {
#pragma unroll
            for (int r = 0; r < 4; ++r) {
                int ri = (q << 2) + r;
#pragma unroll
                for (int j4 = 0; j4 < 4; ++j4)
                    s_f[ri * 68 + j4 * 16 + l15] = ov[(h << 2) + j4][r];
            }
#pragma unroll
            for (int t = 0; t < 4; ++t) {
                int row = (t << 2) + q;
                int p = p0 + (w << 4) + row;
                if (p < N_PTS) {
                    float4 v = *(const float4*)&s_f[row * 68 + l15 * 4];
                    float* dp = (flg[p] & 1) ? (loc + (size_t)p * INC)
                                             : (outp + (size_t)p * INC);
                    *(float4*)(dp + h * 64 + l15 * 4) = v;
                }
            }
        }
    }
}

// ---------------- K_pairs: 16 same-slot pairs per wave, MFMA + scatter ------
__global__ __launch_bounds__(256) void k_pairs(
        const float* __restrict__ F, const __hip_bfloat16* __restrict__ Wp,
        const int* __restrict__ cnt, const int* __restrict__ dst,
        const int* __restrict__ src, float* __restrict__ loc) {
    const int b = blockIdx.x >> 7;            // bucket 0..25 (128 blocks each)
    const int chunk = blockIdx.x & 127;
    int n = cnt[b]; if (n > CAPP) n = CAPP;
    const int wv = threadIdx.x >> 6;
    const int base = chunk * 64 + wv * 16;    // this wave's 16 pairs
    if (base >= n) return;
    const int slot = b < 13 ? b : b + 1;

    const int lane = threadIdx.x & 63;
    const int q = lane >> 4, l15 = lane & 15;
    const int* srcb = src + b * CAPP;
    const int* dstb = dst + b * CAPP;

    int mrow = (base + l15 < n) ? srcb[base + l15] : 0;   // A row per l15
    const bf16x8* Bp = (const bf16x8*)Wp + (size_t)slot * 2048;

    f32x4 acc[8];
#pragma unroll
    for (int j = 0; j < 8; ++j) acc[j] = (f32x4){0.f, 0.f, 0.f, 0.f};

#pragma unroll
    for (int ks = 0; ks < 4; ++ks) {
        bf16x8 a = ld_cvt8(F + (size_t)mrow * INC + ks * 32 + q * 8);
#pragma unroll
        for (int j = 0; j < 8; ++j)
            acc[j] = __builtin_amdgcn_mfma_f32_16x16x32_bf16(a, Bp[(ks * 8 + j) * 64 + lane], acc[j], 0, 0, 0);
    }

#pragma unroll 1
    for (int m = 0; m < 16; ++m) {
        int ri = base + m;
        if (ri >= n) break;
        int d = dstb[ri];
        if (q == (m >> 2)) {
            float* lp = loc + (size_t)d * INC + l15;
            int r = m & 3;
#pragma unroll
            for (int j = 0; j < 8; ++j) atomicAdd(lp + (j << 4), acc[j][r]);
        }
    }
}

// ---------------- K_final: sparse pass over needs-final list ----------------
__global__ __launch_bounds__(256) void k_final(
        const __hip_bfloat16* __restrict__ F_input, const float* __restrict__ loc,
        const float* __restrict__ aux, const int* __restrict__ coords,
        const float* __restrict__ counts_v, const int* __restrict__ aux_idx,
        const float* __restrict__ w_pos, const float* __restrict__ alpha,
        const float* __restrict__ g_local, const float* __restrict__ b_local,
        const float* __restrict__ g_norm, const float* __restrict__ b_norm,
        const int* __restrict__ cnt, const int* __restrict__ ndl,
        float* __restrict__ out) {
    const int tid = threadIdx.x, g = tid >> 4, l15 = tid & 15;
    const int c0 = l15 * 8;
    const int nd = cnt[26];
    if (blockIdx.x * 128 >= nd) return;

    float wpv[24], pa[8], gl[8], bl[8], gn[8], bn[8];
#pragma unroll
    for (int t = 0; t < 6; ++t) ((float4*)wpv)[t] = ((const float4*)(w_pos + c0 * 3))[t];
#pragma unroll
    for (int t = 0; t < 2; ++t) {
        ((float4*)pa)[t] = ((const float4*)(alpha   + c0))[t];
        ((float4*)gl)[t] = ((const float4*)(g_local + c0))[t];
        ((float4*)bl)[t] = ((const float4*)(b_local + c0))[t];
        ((float4*)gn)[t] = ((const float4*)(g_norm  + c0))[t];
        ((float4*)bn)[t] = ((const float4*)(b_norm  + c0))[t];
    }

    for (int base = blockIdx.x * 128; base < nd; base += gridDim.x * 128) {
#pragma unroll 1
        for (int t = 0; t < 8; ++t) {
            int idx = base + t * 16 + g;
            if (idx >= nd) continue;
            int p = ndl[idx];

            float lv[8], s = 0.f, ss = 0.f;
            ((float4*)lv)[0] = *(const float4*)(loc + (size_t)p * INC + c0);
            ((float4*)lv)[1] = *(const float4*)(loc + (size_t)p * INC + c0 + 4);
#pragma unroll
            for (int j = 0; j < 8; ++j) { s += lv[j]; ss += lv[j] * lv[j]; }
#pragma unroll
            for (int m = 1; m < 16; m <<= 1) { s += __shfl_xor(s, m); ss += __shfl_xor(ss, m); }
            float meanL = s * (1.f / 128.f);
            float rstdL = rsqrtf(ss * (1.f / 128.f) - meanL * meanL + 1e-6f);

            float cv = counts_v[p];
            bool multi = cv > 1.5f;
            float invc = 1.f / cv;
            float cx = (float)coords[p * 3 + 0], cy = (float)coords[p * 3 + 1],
                  cz = (float)coords[p * 3 + 2];
            const float* auxp = aux + (size_t)aux_idx[p] * (3 * INC);

            bf16x8 fbv = *(const bf16x8*)(F_input + (size_t)p * INC + c0);
            float nv[8], s2 = 0.f, ss2 = 0.f;
#pragma unroll
            for (int j = 0; j < 8; ++j) {
                int c = c0 + j;
                float f = __bfloat162float(((__hip_bfloat16*)&fbv)[j]);
                float ps = compute_pos3(wpv[j * 3], wpv[j * 3 + 1], wpv[j * 3 + 2], pa[j], cx, cy, cz);
                float sn = __sinf(ps), cs = __cosf(ps);
                float v0, v1, v2;
                if (multi) { v0 = auxp[c] * invc; v1 = auxp[INC + c] * invc; v2 = auxp[2 * INC + c] * invc; }
                else       { v0 = f * cs;         v1 = f * sn;               v2 = f * ps; }
                float nw = v0 * cs + v1 * sn + v2 - f * ps;   // singleton: exact cancel
                nv[j] = nw; s2 += nw; ss2 += nw * nw;
            }
#pragma unroll
            for (int m = 1; m < 16; m <<= 1) { s2 += __shfl_xor(s2, m); ss2 += __shfl_xor(ss2, m); }
            float meanN = s2 * (1.f / 128.f);
            float rstdN = rsqrtf(ss2 * (1.f / 128.f) - meanN * meanN + 1e-6f);
            float ov[8];
#pragma unroll
            for (int j = 0; j < 8; ++j) {
                float nn = (nv[j] - meanN) * rstdN * gn[j] + bn[j];
                float ll = (lv[j] - meanL) * rstdL * gl[j] + bl[j];
                float o = nn + ll;
                ov[j] = o > 0.f ? o : 0.f;
            }
            float4* op = (float4*)(out + (size_t)p * INC + c0);
            op[0] = ((float4*)ov)[0];
            op[1] = ((float4*)ov)[1];
        }
    }
}

// ---------------- host launcher ---------------------------------------------
extern "C" void kernel_launch(void* const* d_in, const int* in_sizes, int n_in,
                              void* d_out, int out_size, void* d_ws, size_t ws_size,
                              hipStream_t stream) {
    (void)in_sizes; (void)n_in; (void)out_size; (void)ws_size;
    const float* F        = (const float*)d_in[0];
    const int*   coords   = (const int*)d_in[1];
    const int*   nbr      = (const int*)d_in[2];
    const int*   aux_idx  = (const int*)d_in[3];
    const float* counts_v = (const float*)d_in[4];
    const float* alpha    = (const float*)d_in[6];
    const float* w_pos    = (const float*)d_in[7];
    const float* w_pre    = (const float*)d_in[8];
    const float* g_pre    = (const float*)d_in[9];
    const float* b_pre    = (const float*)d_in[10];
    const float* w_conv   = (const float*)d_in[11];
    const float* g_local  = (const float*)d_in[12];
    const float* b_local  = (const float*)d_in[13];
    const float* g_norm   = (const float*)d_in[14];
    const float* b_norm   = (const float*)d_in[15];
    float* out = (float*)d_out;

    char* ws = (char*)d_ws;
    __hip_bfloat16* Wp      = (__hip_bfloat16*)(ws + OFF_WP);
    __hip_bfloat16* Wpre    = (__hip_bfloat16*)(ws + OFF_WPRE);
    __hip_bfloat16* F_input = (__hip_bfloat16*)(ws + OFF_FIN);
    float*          loc     = (float*)(ws + OFF_LOC);
    float*          aux     = (float*)(ws + OFF_AUX);
    int*            cnt     = (int*)(ws + OFF_CNT);
    int*            dstb    = (int*)(ws + OFF_DST);
    int*            srcb    = (int*)(ws + OFF_SRC);
    unsigned char*  flg     = (unsigned char*)(ws + OFF_FLG);
    int*            ndl     = (int*)(ws + OFF_NDL);

    const int mt64 = (N_PTS + 63) / 64;           // 1563
    hipMemsetAsync(cnt, 0, SZ_CNT, stream);
    k_prep<<<1792, 256, 0, stream>>>(w_pre, w_conv, Wp, Wpre);
    k_scan<<<391, 256, 0, stream>>>(nbr, counts_v, aux_idx, aux, cnt, dstb, srcb, flg, ndl);
    k_gemm<<<mt64, 256, 0, stream>>>(F, Wpre, Wp, coords, aux_idx, flg,
                                     w_pos, alpha, g_pre, b_pre, g_local, b_local,
                                     g_norm, b_norm, F_input, loc, aux, out);
    k_pairs<<<26 * 128, 256, 0, stream>>>(F, Wp, cnt, dstb, srcb, loc);
    k_final<<<256, 256, 0, stream>>>(F_input, loc, aux, coords, counts_v, aux_idx,
                                     w_pos, alpha, g_local, b_local, g_norm, b_norm,
                                     cnt, ndl, out);
}

// Round 4
// 302.840 us; speedup vs baseline: 1.0433x; 1.0433x over previous
//
#include <hip/hip_runtime.h>
#include <hip/hip_bf16.h>
#include <stdint.h>

#define N_PTS 100000
#define INC 128
#define NSLOT 27
#define CAPP 8192                 // pairs per slot-bucket (expected ~620)
#define SCAP 64                   // LDS staging cap per slot per block

typedef float f32x4 __attribute__((ext_vector_type(4)));
typedef short bf16x8 __attribute__((ext_vector_type(8)));

// ---------------- workspace layout --------------------------------------
static const size_t OFF_WP   = 0;                                        // 27 slots frag-packed bf16
static const size_t SZ_WP    = (size_t)NSLOT * INC * INC * 2;
static const size_t OFF_WPRE = (OFF_WP + SZ_WP + 255) & ~(size_t)255;    // w_pre frag-packed bf16
static const size_t SZ_WPRE  = (size_t)INC * INC * 2;
static const size_t OFF_FIN  = (OFF_WPRE + SZ_WPRE + 255) & ~(size_t)255; // F_input bf16
static const size_t SZ_FIN   = (size_t)N_PTS * INC * 2;
static const size_t OFF_LOC  = (OFF_FIN + SZ_FIN + 255) & ~(size_t)255;   // local accum f32
static const size_t SZ_LOC   = (size_t)N_PTS * INC * 4;
static const size_t OFF_AUX  = (OFF_LOC + SZ_LOC + 255) & ~(size_t)255;   // aux rows f32 (by aux_idx)
static const size_t SZ_AUX   = (size_t)N_PTS * 3 * INC * 4;
static const size_t OFF_CNT  = (OFF_AUX + SZ_AUX + 255) & ~(size_t)255;   // 26 bucket counters + [26]=ndl count
static const size_t SZ_CNT   = 128;
static const size_t OFF_DST  = (OFF_CNT + SZ_CNT + 255) & ~(size_t)255;
static const size_t SZ_DST   = (size_t)26 * CAPP * 4;
static const size_t OFF_SRC  = (OFF_DST + SZ_DST + 255) & ~(size_t)255;
static const size_t SZ_SRC   = (size_t)26 * CAPP * 4;
static const size_t OFF_FLG  = (OFF_SRC + SZ_SRC + 255) & ~(size_t)255;   // per-point flags u8
static const size_t SZ_FLG   = (size_t)N_PTS;
static const size_t OFF_NDL  = (OFF_FLG + SZ_FLG + 255) & ~(size_t)255;   // needs-final point list
static const size_t SZ_NDL   = (size_t)N_PTS * 4;                          // total ~234.5 MB

#define PREP_BLOCKS 1792
#define SCAN_BLOCKS 391

__device__ __forceinline__ float compute_pos3(float w0, float w1, float w2, float a,
                                              float cx, float cy, float cz) {
    return (cx * w0 + cy * w1 + cz * w2) * a;
}

// load 8 consecutive f32 and round to a bf16x8 MFMA fragment
__device__ __forceinline__ bf16x8 ld_cvt8(const float* __restrict__ p) {
    const float4 u = *(const float4*)p;
    const float4 v = *(const float4*)(p + 4);
    bf16x8 r;
    __hip_bfloat16* h = (__hip_bfloat16*)&r;
    h[0] = __float2bfloat16(u.x); h[1] = __float2bfloat16(u.y);
    h[2] = __float2bfloat16(u.z); h[3] = __float2bfloat16(u.w);
    h[4] = __float2bfloat16(v.x); h[5] = __float2bfloat16(v.y);
    h[6] = __float2bfloat16(v.z); h[7] = __float2bfloat16(v.w);
    return r;
}

// ---------------- K_front: weight pack (blocks < PREP_BLOCKS) + scan --------
__global__ __launch_bounds__(256) void k_front(
        const float* __restrict__ w_pre, const float* __restrict__ w_conv,
        __hip_bfloat16* __restrict__ Wp, __hip_bfloat16* __restrict__ Wpre,
        const int* __restrict__ nbr_idx, const float* __restrict__ counts_v,
        const int* __restrict__ aux_idx, float* __restrict__ aux,
        int* __restrict__ cnt, int* __restrict__ dst, int* __restrict__ src,
        unsigned char* __restrict__ flg, int* __restrict__ ndl) {
    __shared__ int s_cnt[26], s_base[26];
    __shared__ int s_dst[26][SCAP], s_src[26][SCAP];

    const int tid = threadIdx.x;

    if (blockIdx.x < PREP_BLOCKS) {
        // ---- prep part: pack weights (coalesced source reads) ----
        int i = blockIdx.x * 256 + tid;
        if (i < 16384) {                        // w_pre: B[n=d][k=c] = w_pre[d*128+c]
            int d = i >> 7, c = i & 127;
            int j = ((c >> 5) << 12) | ((d >> 4) << 9)
                  | (((((c >> 3) & 3) << 4) + (d & 15)) << 3) | (c & 7);
            Wpre[j] = __float2bfloat16(w_pre[i]);
        } else if (i < 16384 + NSLOT * 16384) { // w_conv: B[n=d][k=c] = w_conv[slot][c][d]
            int t = i - 16384;
            int slot = t >> 14, rem = t & 16383;
            int c = rem >> 7, d = rem & 127;
            int j = (slot << 14) | ((c >> 5) << 12) | ((d >> 4) << 9)
                  | (((((c >> 3) & 3) << 4) + (d & 15)) << 3) | (c & 7);
            Wp[j] = __float2bfloat16(w_conv[t]);
        }
        return;
    }

    // ---- scan part: pair compaction + flags + needs-final list ----
    const int lane = tid & 63;
    const int p = (blockIdx.x - PREP_BLOCKS) * 256 + tid;
    const bool vp = p < N_PTS;

    if (tid < 26) s_cnt[tid] = 0;
    __syncthreads();

    float cv = vp ? counts_v[p] : 0.f;
    bool multi = cv > 1.5f;
    if (multi) {                             // zero this point's cell aux row (idempotent)
        float4* row = (float4*)(aux + (size_t)aux_idx[p] * (3 * INC));
#pragma unroll
        for (int i = 0; i < (3 * INC) / 4; ++i) row[i] = make_float4(0.f, 0.f, 0.f, 0.f);
    }

    const int* nb = nbr_idx + (size_t)p * NSLOT;
    bool hn = false;
#pragma unroll 1
    for (int k = 0; k < NSLOT; ++k) {
        if (k == 13) continue;               // self handled densely
        int m = vp ? nb[k] : N_PTS;
        if (m < N_PTS) {
            hn = true;
            int b = k < 13 ? k : k - 1;      // 0..25
            int li = atomicAdd(&s_cnt[b], 1);
            if (li < SCAP) { s_dst[b][li] = p; s_src[b][li] = m; }
            else {
                int gi = atomicAdd(&cnt[b], 1);
                if (gi < CAPP) { dst[b * CAPP + gi] = p; src[b * CAPP + gi] = m; }
            }
        }
    }

    // flags: bit0 = needs k_final (multi or has occupied neighbor), bit1 = multi
    bool nd = vp && (hn || multi);
    if (vp) flg[p] = (unsigned char)((nd ? 1 : 0) | (multi ? 2 : 0));
    unsigned long long mb = __ballot(nd);
    int basew = 0;
    if (lane == 0 && mb) basew = atomicAdd(&cnt[26], __popcll(mb));
    basew = __shfl(basew, 0);
    if (nd) ndl[basew + __popcll(mb & ((1ull << lane) - 1))] = p;

    __syncthreads();

    if (tid < 26) {
        int n = s_cnt[tid]; if (n > SCAP) n = SCAP;
        s_base[tid] = n > 0 ? atomicAdd(&cnt[tid], n) : 0;
        s_cnt[tid] = n;
    }
    __syncthreads();

    for (int b = tid >> 3; b < 26; b += 32) {
        int n = s_cnt[b], base = s_base[b];
        for (int e = tid & 7; e < n; e += 8) {
            int gi = base + e;
            if (gi < CAPP) { dst[b * CAPP + gi] = s_dst[b][e]; src[b * CAPP + gi] = s_src[b][e]; }
        }
    }
}

// ---------------- K_gemm: pre_mix + self-conv GEMMs, fused final for done rows
// 16 rows/wave (6250 waves for TLP). Register diet vs R3: fj[4][8] (LN_pre
// output) lives in REGISTERS across both passes -- MFMA's C layout means this
// thread holds the same (row,col) positions in pass L, so no LDS round-trip
// and no ov[] array (outputs staged to s_f directly per r). a[4] loaded once.
// launch_bounds(256,4): 128-VGPR cap, est. peak live ~103 -> no spill.
// LDS: 4 waves x 8448 (f32 [16][132] / bf16 [16][136] time-shared) + 3 KB.
__global__ __launch_bounds__(256, 4) void k_gemm(
        const float* __restrict__ F, const __hip_bfloat16* __restrict__ Wpre,
        const __hip_bfloat16* __restrict__ Wp, const int* __restrict__ coords,
        const int* __restrict__ aux_idx, const unsigned char* __restrict__ flg,
        const float* __restrict__ w_pos, const float* __restrict__ alpha,
        const float* __restrict__ g_pre, const float* __restrict__ b_pre,
        const float* __restrict__ g_local, const float* __restrict__ b_local,
        const float* __restrict__ g_norm, const float* __restrict__ b_norm,
        __hip_bfloat16* __restrict__ F_input, float* __restrict__ loc,
        float* __restrict__ aux, float* __restrict__ outp) {
    __shared__ char s_buf[4][8448];            // per-wave, time-shared
    __shared__ float s_gp[INC], s_bp[INC], s_gl[INC], s_bl[INC], s_gn[INC], s_bn[INC];

    const int tid = threadIdx.x, w = tid >> 6, lane = tid & 63;
    const int q = lane >> 4, l15 = lane & 15;
    const int p0 = blockIdx.x * 64;

    if (tid < INC) {
        s_gp[tid] = g_pre[tid];   s_bp[tid] = b_pre[tid];
        s_gl[tid] = g_local[tid]; s_bl[tid] = b_local[tid];
        s_gn[tid] = g_norm[tid];  s_bn[tid] = b_norm[tid];
    }
    __syncthreads();

    int grow = p0 + (w << 4) + l15;
    if (grow >= N_PTS) grow = N_PTS - 1;      // clamp; stores guarded

    const float* A = F + (size_t)grow * INC + q * 8;

    __hip_bfloat16* s_bf = (__hip_bfloat16*)s_buf[w];   // [16][136] bf16 (F_input staging)
    float*          s_f  = (float*)s_buf[w];            // [16][132] f32 (out staging, later)

    // A fragments: load + convert ONCE, reuse in both passes
    bf16x8 a[4];
#pragma unroll
    for (int ks = 0; ks < 4; ++ks) a[ks] = ld_cvt8(A + ks * 32);

    float fj[4][8];                            // LN_pre outputs, kept in regs

    // ================= pass P: pre_mix GEMM =================
    {
        const bf16x8* Bp = (const bf16x8*)Wpre;
        f32x4 acc[8];
#pragma unroll
        for (int j = 0; j < 8; ++j) acc[j] = (f32x4){0.f, 0.f, 0.f, 0.f};
#pragma unroll
        for (int ks = 0; ks < 4; ++ks) {
#pragma unroll
            for (int j = 0; j < 8; ++j) {
                bf16x8 b = Bp[(ks * 8 + j) * 64 + lane];
                acc[j] = __builtin_amdgcn_mfma_f32_16x16x32_bf16(a[ks], b, acc[j], 0, 0, 0);
            }
        }
        // LN_pre epilogue -> fj regs + bf16 LDS (store staging) + aux atomics
#pragma unroll
        for (int r = 0; r < 4; ++r) {
            int ri = (q << 2) + r;
            int p = p0 + (w << 4) + ri;
            float s = 0.f, ss = 0.f;
#pragma unroll
            for (int j = 0; j < 8; ++j) { float v = acc[j][r]; fj[r][j] = v; s += v; ss += v * v; }
#pragma unroll
            for (int m = 1; m < 16; m <<= 1) { s += __shfl_xor(s, m); ss += __shfl_xor(ss, m); }
            float mean = s * (1.f / 128.f);
            float rstd = rsqrtf(ss * (1.f / 128.f) - mean * mean + 1e-6f);
            bool multi = p < N_PTS && (flg[p] & 2);
            float cx = 0.f, cy = 0.f, cz = 0.f;
            float* auxp = aux;
            if (multi) {
                cx = (float)coords[p * 3 + 0]; cy = (float)coords[p * 3 + 1];
                cz = (float)coords[p * 3 + 2];
                auxp = aux + (size_t)aux_idx[p] * (3 * INC);
            }
#pragma unroll
            for (int j = 0; j < 8; ++j) {
                int c = (j << 4) + l15;
                float fi = (fj[r][j] - mean) * rstd * s_gp[c] + s_bp[c];
                __hip_bfloat16 fb = __float2bfloat16(fi);
                s_bf[ri * 136 + c] = fb;
                float fr = __bfloat162float(fb);
                fj[r][j] = fr;                 // keep quantized value (matches ref numerics)
                if (multi) {
                    const float* wp = w_pos + c * 3;
                    float ps = compute_pos3(wp[0], wp[1], wp[2], alpha[c], cx, cy, cz);
                    float sn = __sinf(ps), cs = __cosf(ps);
                    atomicAdd(auxp + c,           fr * cs);
                    atomicAdd(auxp + INC + c,     fr * sn);
                    atomicAdd(auxp + 2 * INC + c, fr * ps);
                }
            }
        }
        // F_input store only for needs-final rows
#pragma unroll
        for (int t = 0; t < 4; ++t) {
            int row = (t << 2) + q;
            int p = p0 + (w << 4) + row;
            if (p < N_PTS && (flg[p] & 1)) {
                bf16x8 v = *(const bf16x8*)&s_bf[row * 136 + l15 * 8];
                *(bf16x8*)(F_input + (size_t)p * INC + l15 * 8) = v;
            }
        }
    }

    // ================= pass L: self-slot conv GEMM + fused final ============
    {
        const bf16x8* Bp = (const bf16x8*)Wp + (size_t)13 * 2048;   // self slot
        f32x4 acc[8];
#pragma unroll
        for (int j = 0; j < 8; ++j) acc[j] = (f32x4){0.f, 0.f, 0.f, 0.f};
#pragma unroll
        for (int ks = 0; ks < 4; ++ks) {
#pragma unroll
            for (int j = 0; j < 8; ++j) {
                bf16x8 b = Bp[(ks * 8 + j) * 64 + lane];
                acc[j] = __builtin_amdgcn_mfma_f32_16x16x32_bf16(a[ks], b, acc[j], 0, 0, 0);
            }
        }
        // fused epilogue: done rows -> out = relu(LN(F_input) + LN(local));
        //                 needs-final rows -> raw local conv. Staged per-r into
        //                 s_f (aliases s_bf; all s_bf reads completed above).
#pragma unroll
        for (int r = 0; r < 4; ++r) {
            int ri = (q << 2) + r;
            int p = p0 + (w << 4) + ri;
            int fl = (p < N_PTS) ? flg[p] : 1;
            float lv[8], sL = 0.f, ssL = 0.f, sN = 0.f, ssN = 0.f;
#pragma unroll
            for (int j = 0; j < 8; ++j) {
                float v = acc[j][r]; lv[j] = v; sL += v; ssL += v * v;
                float f = fj[r][j];  sN += f; ssN += f * f;
            }
#pragma unroll
            for (int m = 1; m < 16; m <<= 1) {
                sL += __shfl_xor(sL, m); ssL += __shfl_xor(ssL, m);
                sN += __shfl_xor(sN, m); ssN += __shfl_xor(ssN, m);
            }
            float meanL = sL * (1.f / 128.f);
            float rstdL = rsqrtf(ssL * (1.f / 128.f) - meanL * meanL + 1e-6f);
            float meanN = sN * (1.f / 128.f);
            float rstdN = rsqrtf(ssN * (1.f / 128.f) - meanN * meanN + 1e-6f);
#pragma unroll
            for (int j = 0; j < 8; ++j) {
                int c = (j << 4) + l15;
                float nn = (fj[r][j] - meanN) * rstdN * s_gn[c] + s_bn[c];
                float ll = (lv[j] - meanL) * rstdL * s_gl[c] + s_bl[c];
                float o = nn + ll; o = o > 0.f ? o : 0.f;
                s_f[ri * 132 + c] = (fl & 1) ? lv[j] : o;
            }
        }
        // coalesced store; per-row destination = needs-final ? loc : out
#pragma unroll
        for (int t = 0; t < 4; ++t) {
            int row = (t << 2) + q;
            int p = p0 + (w << 4) + row;
            if (p < N_PTS) {
                float4 v0 = *(const float4*)&s_f[row * 132 + l15 * 8];
                float4 v1 = *(const float4*)&s_f[row * 132 + l15 * 8 + 4];
                float* dp = (flg[p] & 1) ? (loc + (size_t)p * INC)
                                         : (outp + (size_t)p * INC);
                *(float4*)(dp + l15 * 8)     = v0;
                *(float4*)(dp + l15 * 8 + 4) = v1;
            }
        }
    }
}

// ---------------- K_pairs: 16 same-slot pairs per wave, MFMA + scatter ------
__global__ __launch_bounds__(256) void k_pairs(
        const float* __restrict__ F, const __hip_bfloat16* __restrict__ Wp,
        const int* __restrict__ cnt, const int* __restrict__ dst,
        const int* __restrict__ src, float* __restrict__ loc) {
    const int b = blockIdx.x >> 7;            // bucket 0..25 (128 blocks each)
    const int chunk = blockIdx.x & 127;
    int n = cnt[b]; if (n > CAPP) n = CAPP;
    const int wv = threadIdx.x >> 6;
    const int base = chunk * 64 + wv * 16;    // this wave's 16 pairs
    if (base >= n) return;
    const int slot = b < 13 ? b : b + 1;

    const int lane = threadIdx.x & 63;
    const int q = lane >> 4, l15 = lane & 15;
    const int* srcb = src + b * CAPP;
    const int* dstb = dst + b * CAPP;

    int mrow = (base + l15 < n) ? srcb[base + l15] : 0;   // A row per l15
    const bf16x8* Bp = (const bf16x8*)Wp + (size_t)slot * 2048;

    f32x4 acc[8];
#pragma unroll
    for (int j = 0; j < 8; ++j) acc[j] = (f32x4){0.f, 0.f, 0.f, 0.f};

#pragma unroll
    for (int ks = 0; ks < 4; ++ks) {
        bf16x8 a = ld_cvt8(F + (size_t)mrow * INC + ks * 32 + q * 8);
#pragma unroll
        for (int j = 0; j < 8; ++j)
            acc[j] = __builtin_amdgcn_mfma_f32_16x16x32_bf16(a, Bp[(ks * 8 + j) * 64 + lane], acc[j], 0, 0, 0);
    }

#pragma unroll 1
    for (int m = 0; m < 16; ++m) {
        int ri = base + m;
        if (ri >= n) break;
        int d = dstb[ri];
        if (q == (m >> 2)) {
            float* lp = loc + (size_t)d * INC + l15;
            int r = m & 3;
#pragma unroll
            for (int j = 0; j < 8; ++j) atomicAdd(lp + (j << 4), acc[j][r]);
        }
    }
}

// ---------------- K_final: sparse pass over needs-final list ----------------
__global__ __launch_bounds__(256) void k_final(
        const __hip_bfloat16* __restrict__ F_input, const float* __restrict__ loc,
        const float* __restrict__ aux, const int* __restrict__ coords,
        const float* __restrict__ counts_v, const int* __restrict__ aux_idx,
        const float* __restrict__ w_pos, const float* __restrict__ alpha,
        const float* __restrict__ g_local, const float* __restrict__ b_local,
        const float* __restrict__ g_norm, const float* __restrict__ b_norm,
        const int* __restrict__ cnt, const int* __restrict__ ndl,
        float* __restrict__ out) {
    const int tid = threadIdx.x, g = tid >> 4, l15 = tid & 15;
    const int c0 = l15 * 8;
    const int nd = cnt[26];
    if (blockIdx.x * 128 >= nd) return;

    float wpv[24], pa[8], gl[8], bl[8], gn[8], bn[8];
#pragma unroll
    for (int t = 0; t < 6; ++t) ((float4*)wpv)[t] = ((const float4*)(w_pos + c0 * 3))[t];
#pragma unroll
    for (int t = 0; t < 2; ++t) {
        ((float4*)pa)[t] = ((const float4*)(alpha   + c0))[t];
        ((float4*)gl)[t] = ((const float4*)(g_local + c0))[t];
        ((float4*)bl)[t] = ((const float4*)(b_local + c0))[t];
        ((float4*)gn)[t] = ((const float4*)(g_norm  + c0))[t];
        ((float4*)bn)[t] = ((const float4*)(b_norm  + c0))[t];
    }

    for (int base = blockIdx.x * 128; base < nd; base += gridDim.x * 128) {
#pragma unroll 1
        for (int t = 0; t < 8; ++t) {
            int idx = base + t * 16 + g;
            if (idx >= nd) continue;
            int p = ndl[idx];

            float lv[8], s = 0.f, ss = 0.f;
            ((float4*)lv)[0] = *(const float4*)(loc + (size_t)p * INC + c0);
            ((float4*)lv)[1] = *(const float4*)(loc + (size_t)p * INC + c0 + 4);
#pragma unroll
            for (int j = 0; j < 8; ++j) { s += lv[j]; ss += lv[j] * lv[j]; }
#pragma unroll
            for (int m = 1; m < 16; m <<= 1) { s += __shfl_xor(s, m); ss += __shfl_xor(ss, m); }
            float meanL = s * (1.f / 128.f);
            float rstdL = rsqrtf(ss * (1.f / 128.f) - meanL * meanL + 1e-6f);

            float cv = counts_v[p];
            bool multi = cv > 1.5f;
            float invc = 1.f / cv;
            float cx = (float)coords[p * 3 + 0], cy = (float)coords[p * 3 + 1],
                  cz = (float)coords[p * 3 + 2];
            const float* auxp = aux + (size_t)aux_idx[p] * (3 * INC);

            bf16x8 fbv = *(const bf16x8*)(F_input + (size_t)p * INC + c0);
            float nv[8], s2 = 0.f, ss2 = 0.f;
#pragma unroll
            for (int j = 0; j < 8; ++j) {
                int c = c0 + j;
                float f = __bfloat162float(((__hip_bfloat16*)&fbv)[j]);
                float ps = compute_pos3(wpv[j * 3], wpv[j * 3 + 1], wpv[j * 3 + 2], pa[j], cx, cy, cz);
                float sn = __sinf(ps), cs = __cosf(ps);
                float v0, v1, v2;
                if (multi) { v0 = auxp[c] * invc; v1 = auxp[INC + c] * invc; v2 = auxp[2 * INC + c] * invc; }
                else       { v0 = f * cs;         v1 = f * sn;               v2 = f * ps; }
                float nw = v0 * cs + v1 * sn + v2 - f * ps;   // singleton: exact cancel
                nv[j] = nw; s2 += nw; ss2 += nw * nw;
            }
#pragma unroll
            for (int m = 1; m < 16; m <<= 1) { s2 += __shfl_xor(s2, m); ss2 += __shfl_xor(ss2, m); }
            float meanN = s2 * (1.f / 128.f);
            float rstdN = rsqrtf(ss2 * (1.f / 128.f) - meanN * meanN + 1e-6f);
            float ov[8];
#pragma unroll
            for (int j = 0; j < 8; ++j) {
                float nn = (nv[j] - meanN) * rstdN * gn[j] + bn[j];
                float ll = (lv[j] - meanL) * rstdL * gl[j] + bl[j];
                float o = nn + ll;
                ov[j] = o > 0.f ? o : 0.f;
            }
            float4* op = (float4*)(out + (size_t)p * INC + c0);
            op[0] = ((float4*)ov)[0];
            op[1] = ((float4*)ov)[1];
        }
    }
}

// ---------------- host launcher ---------------------------------------------
extern "C" void kernel_launch(void* const* d_in, const int* in_sizes, int n_in,
                              void* d_out, int out_size, void* d_ws, size_t ws_size,
                              hipStream_t stream) {
    (void)in_sizes; (void)n_in; (void)out_size; (void)ws_size;
    const float* F        = (const float*)d_in[0];
    const int*   coords   = (const int*)d_in[1];
    const int*   nbr      = (const int*)d_in[2];
    const int*   aux_idx  = (const int*)d_in[3];
    const float* counts_v = (const float*)d_in[4];
    const float* alpha    = (const float*)d_in[6];
    const float* w_pos    = (const float*)d_in[7];
    const float* w_pre    = (const float*)d_in[8];
    const float* g_pre    = (const float*)d_in[9];
    const float* b_pre    = (const float*)d_in[10];
    const float* w_conv   = (const float*)d_in[11];
    const float* g_local  = (const float*)d_in[12];
    const float* b_local  = (const float*)d_in[13];
    const float* g_norm   = (const float*)d_in[14];
    const float* b_norm   = (const float*)d_in[15];
    float* out = (float*)d_out;

    char* ws = (char*)d_ws;
    __hip_bfloat16* Wp      = (__hip_bfloat16*)(ws + OFF_WP);
    __hip_bfloat16* Wpre    = (__hip_bfloat16*)(ws + OFF_WPRE);
    __hip_bfloat16* F_input = (__hip_bfloat16*)(ws + OFF_FIN);
    float*          loc     = (float*)(ws + OFF_LOC);
    float*          aux     = (float*)(ws + OFF_AUX);
    int*            cnt     = (int*)(ws + OFF_CNT);
    int*            dstb    = (int*)(ws + OFF_DST);
    int*            srcb    = (int*)(ws + OFF_SRC);
    unsigned char*  flg     = (unsigned char*)(ws + OFF_FLG);
    int*            ndl     = (int*)(ws + OFF_NDL);

    const int mt64 = (N_PTS + 63) / 64;           // 1563
    hipMemsetAsync(cnt, 0, SZ_CNT, stream);
    k_front<<<PREP_BLOCKS + SCAN_BLOCKS, 256, 0, stream>>>(
        w_pre, w_conv, Wp, Wpre, nbr, counts_v, aux_idx, aux, cnt, dstb, srcb, flg, ndl);
    k_gemm<<<mt64, 256, 0, stream>>>(F, Wpre, Wp, coords, aux_idx, flg,
                                     w_pos, alpha, g_pre, b_pre, g_local, b_local,
                                     g_norm, b_norm, F_input, loc, aux, out);
    k_pairs<<<26 * 128, 256, 0, stream>>>(F, Wp, cnt, dstb, srcb, loc);
    k_final<<<256, 256, 0, stream>>>(F_input, loc, aux, coords, counts_v, aux_idx,
                                     w_pos, alpha, g_local, b_local, g_norm, b_norm,
                                     cnt, ndl, out);
}

// Round 5
// 259.924 us; speedup vs baseline: 1.2156x; 1.1651x over previous
//
#include <hip/hip_runtime.h>
#include <hip/hip_bf16.h>
#include <stdint.h>

#define N_PTS 100000
#define INC 128
#define NSLOT 27
#define CAPP 8192                 // pairs per slot-bucket (expected ~620)
#define SCAP 64                   // LDS staging cap per slot per block

typedef float f32x4 __attribute__((ext_vector_type(4)));
typedef short bf16x8 __attribute__((ext_vector_type(8)));

// ---------------- workspace layout --------------------------------------
static const size_t OFF_WP   = 0;                                        // 27 slots frag-packed bf16
static const size_t SZ_WP    = (size_t)NSLOT * INC * INC * 2;
static const size_t OFF_WPRE = (OFF_WP + SZ_WP + 255) & ~(size_t)255;    // w_pre frag-packed bf16
static const size_t SZ_WPRE  = (size_t)INC * INC * 2;
static const size_t OFF_FIN  = (OFF_WPRE + SZ_WPRE + 255) & ~(size_t)255; // F_input bf16
static const size_t SZ_FIN   = (size_t)N_PTS * INC * 2;
static const size_t OFF_LOC  = (OFF_FIN + SZ_FIN + 255) & ~(size_t)255;   // local accum f32
static const size_t SZ_LOC   = (size_t)N_PTS * INC * 4;
static const size_t OFF_CNT  = (OFF_LOC + SZ_LOC + 255) & ~(size_t)255;   // 26 bucket counters + [26]=ndl count
static const size_t SZ_CNT   = 128;
static const size_t OFF_DST  = (OFF_CNT + SZ_CNT + 255) & ~(size_t)255;
static const size_t SZ_DST   = (size_t)26 * CAPP * 4;
static const size_t OFF_SRC  = (OFF_DST + SZ_DST + 255) & ~(size_t)255;
static const size_t SZ_SRC   = (size_t)26 * CAPP * 4;
static const size_t OFF_FLG  = (OFF_SRC + SZ_SRC + 255) & ~(size_t)255;   // per-point flags u8
static const size_t SZ_FLG   = (size_t)N_PTS;
static const size_t OFF_NDL  = (OFF_FLG + SZ_FLG + 255) & ~(size_t)255;   // needs-final point list
static const size_t SZ_NDL   = (size_t)N_PTS * 4;                          // total ~80 MB (aux eliminated)

#define PREP_BLOCKS 1792
#define SCAN_BLOCKS 391

__device__ __forceinline__ float compute_pos3(float w0, float w1, float w2, float a,
                                              float cx, float cy, float cz) {
    return (cx * w0 + cy * w1 + cz * w2) * a;
}

// load 8 consecutive f32 and round to a bf16x8 MFMA fragment
__device__ __forceinline__ bf16x8 ld_cvt8(const float* __restrict__ p) {
    const float4 u = *(const float4*)p;
    const float4 v = *(const float4*)(p + 4);
    bf16x8 r;
    __hip_bfloat16* h = (__hip_bfloat16*)&r;
    h[0] = __float2bfloat16(u.x); h[1] = __float2bfloat16(u.y);
    h[2] = __float2bfloat16(u.z); h[3] = __float2bfloat16(u.w);
    h[4] = __float2bfloat16(v.x); h[5] = __float2bfloat16(v.y);
    h[6] = __float2bfloat16(v.z); h[7] = __float2bfloat16(v.w);
    return r;
}

// ---------------- K_front: weight pack (blocks < PREP_BLOCKS) + scan --------
__global__ __launch_bounds__(256) void k_front(
        const float* __restrict__ w_pre, const float* __restrict__ w_conv,
        __hip_bfloat16* __restrict__ Wp, __hip_bfloat16* __restrict__ Wpre,
        const int* __restrict__ nbr_idx, const float* __restrict__ counts_v,
        int* __restrict__ cnt, int* __restrict__ dst, int* __restrict__ src,
        unsigned char* __restrict__ flg, int* __restrict__ ndl) {
    __shared__ int s_cnt[26], s_base[26];
    __shared__ int s_dst[26][SCAP], s_src[26][SCAP];

    const int tid = threadIdx.x;

    if (blockIdx.x < PREP_BLOCKS) {
        // ---- prep part: pack weights (coalesced source reads) ----
        int i = blockIdx.x * 256 + tid;
        if (i < 16384) {                        // w_pre: B[n=d][k=c] = w_pre[d*128+c]
            int d = i >> 7, c = i & 127;
            int j = ((c >> 5) << 12) | ((d >> 4) << 9)
                  | (((((c >> 3) & 3) << 4) + (d & 15)) << 3) | (c & 7);
            Wpre[j] = __float2bfloat16(w_pre[i]);
        } else if (i < 16384 + NSLOT * 16384) { // w_conv: B[n=d][k=c] = w_conv[slot][c][d]
            int t = i - 16384;
            int slot = t >> 14, rem = t & 16383;
            int c = rem >> 7, d = rem & 127;
            int j = (slot << 14) | ((c >> 5) << 12) | ((d >> 4) << 9)
                  | (((((c >> 3) & 3) << 4) + (d & 15)) << 3) | (c & 7);
            Wp[j] = __float2bfloat16(w_conv[t]);
        }
        return;
    }

    // ---- scan part: pair compaction + flags + needs-final list ----
    const int lane = tid & 63;
    const int p = (blockIdx.x - PREP_BLOCKS) * 256 + tid;
    const bool vp = p < N_PTS;

    if (tid < 26) s_cnt[tid] = 0;
    __syncthreads();

    float cv = vp ? counts_v[p] : 0.f;
    bool multi = cv > 1.5f;

    const int* nb = nbr_idx + (size_t)p * NSLOT;
    bool hn = false;
#pragma unroll 1
    for (int k = 0; k < NSLOT; ++k) {
        if (k == 13) continue;               // self handled densely
        int m = vp ? nb[k] : N_PTS;
        if (m < N_PTS) {
            hn = true;
            int b = k < 13 ? k : k - 1;      // 0..25
            int li = atomicAdd(&s_cnt[b], 1);
            if (li < SCAP) { s_dst[b][li] = p; s_src[b][li] = m; }
            else {
                int gi = atomicAdd(&cnt[b], 1);
                if (gi < CAPP) { dst[b * CAPP + gi] = p; src[b * CAPP + gi] = m; }
            }
        }
    }

    // flags: bit0 = needs k_final (multi or has occupied neighbor)
    bool nd = vp && (hn || multi);
    if (vp) flg[p] = (unsigned char)(nd ? 1 : 0);
    unsigned long long mb = __ballot(nd);
    int basew = 0;
    if (lane == 0 && mb) basew = atomicAdd(&cnt[26], __popcll(mb));
    basew = __shfl(basew, 0);
    if (nd) ndl[basew + __popcll(mb & ((1ull << lane) - 1))] = p;

    __syncthreads();

    if (tid < 26) {
        int n = s_cnt[tid]; if (n > SCAP) n = SCAP;
        s_base[tid] = n > 0 ? atomicAdd(&cnt[tid], n) : 0;
        s_cnt[tid] = n;
    }
    __syncthreads();

    for (int b = tid >> 3; b < 26; b += 32) {
        int n = s_cnt[b], base = s_base[b];
        for (int e = tid & 7; e < n; e += 8) {
            int gi = base + e;
            if (gi < CAPP) { dst[b * CAPP + gi] = s_dst[b][e]; src[b * CAPP + gi] = s_src[b][e]; }
        }
    }
}

// ---------------- K_gemm: merged pre_mix + self-conv GEMM, fused final ------
// 16 rows/wave, 6250 waves. ONE interleaved MFMA loop (accP + accL, 2x B-load
// MLP), ONE epilogue. No aux atomics (vox handled by gather in k_final).
// No f32 out-staging LDS: direct dword stores (64B-segment coalesced per
// quarter-wave). LDS = 4 x 4352 (bf16 F_input staging) + 3 KB = 20480 B.
__global__ __launch_bounds__(256, 4) void k_gemm(
        const float* __restrict__ F, const __hip_bfloat16* __restrict__ Wpre,
        const __hip_bfloat16* __restrict__ Wp, const unsigned char* __restrict__ flg,
        const float* __restrict__ g_pre, const float* __restrict__ b_pre,
        const float* __restrict__ g_local, const float* __restrict__ b_local,
        const float* __restrict__ g_norm, const float* __restrict__ b_norm,
        __hip_bfloat16* __restrict__ F_input, float* __restrict__ loc,
        float* __restrict__ outp) {
    __shared__ __hip_bfloat16 s_bf[4][16 * 136];   // per-wave F_input staging
    __shared__ float s_gp[INC], s_bp[INC], s_gl[INC], s_bl[INC], s_gn[INC], s_bn[INC];

    const int tid = threadIdx.x, w = tid >> 6, lane = tid & 63;
    const int q = lane >> 4, l15 = lane & 15;
    const int p0 = blockIdx.x * 64;

    if (tid < INC) {
        s_gp[tid] = g_pre[tid];   s_bp[tid] = b_pre[tid];
        s_gl[tid] = g_local[tid]; s_bl[tid] = b_local[tid];
        s_gn[tid] = g_norm[tid];  s_bn[tid] = b_norm[tid];
    }
    __syncthreads();

    int grow = p0 + (w << 4) + l15;
    if (grow >= N_PTS) grow = N_PTS - 1;      // clamp; stores guarded

    const float* A = F + (size_t)grow * INC + q * 8;

    // A fragments: load + convert ONCE, shared by both GEMMs
    bf16x8 a[4];
#pragma unroll
    for (int ks = 0; ks < 4; ++ks) a[ks] = ld_cvt8(A + ks * 32);

    // ---- merged MFMA loop: pre_mix (accP) + self-conv (accL) ----
    const bf16x8* BpP = (const bf16x8*)Wpre;
    const bf16x8* BpL = (const bf16x8*)Wp + (size_t)13 * 2048;
    f32x4 accP[8], accL[8];
#pragma unroll
    for (int j = 0; j < 8; ++j) {
        accP[j] = (f32x4){0.f, 0.f, 0.f, 0.f};
        accL[j] = (f32x4){0.f, 0.f, 0.f, 0.f};
    }
#pragma unroll
    for (int ks = 0; ks < 4; ++ks) {
#pragma unroll
        for (int j = 0; j < 8; ++j) {
            bf16x8 bP = BpP[(ks * 8 + j) * 64 + lane];
            bf16x8 bL = BpL[(ks * 8 + j) * 64 + lane];
            accP[j] = __builtin_amdgcn_mfma_f32_16x16x32_bf16(a[ks], bP, accP[j], 0, 0, 0);
            accL[j] = __builtin_amdgcn_mfma_f32_16x16x32_bf16(a[ks], bL, accL[j], 0, 0, 0);
        }
    }

    // ---- merged epilogue per row ----
    __hip_bfloat16* sb = s_bf[w];
#pragma unroll
    for (int r = 0; r < 4; ++r) {
        int ri = (q << 2) + r;
        int p = p0 + (w << 4) + ri;
        int fl = (p < N_PTS) ? flg[p] : 1;

        // reduce pre_mix row stats
        float s = 0.f, ss = 0.f;
#pragma unroll
        for (int j = 0; j < 8; ++j) { float v = accP[j][r]; s += v; ss += v * v; }
#pragma unroll
        for (int m = 1; m < 16; m <<= 1) { s += __shfl_xor(s, m); ss += __shfl_xor(ss, m); }
        float mean = s * (1.f / 128.f);
        float rstd = rsqrtf(ss * (1.f / 128.f) - mean * mean + 1e-6f);

        // LN_pre -> fj (bf16-quantized, matches F_input numerics) + staging
        float fj[8], sN = 0.f, ssN = 0.f, sL = 0.f, ssL = 0.f;
#pragma unroll
        for (int j = 0; j < 8; ++j) {
            int c = (j << 4) + l15;
            float fi = (accP[j][r] - mean) * rstd * s_gp[c] + s_bp[c];
            __hip_bfloat16 fb = __float2bfloat16(fi);
            sb[ri * 136 + c] = fb;
            float f = __bfloat162float(fb);
            fj[j] = f; sN += f; ssN += f * f;
            float v = accL[j][r]; sL += v; ssL += v * v;
        }
#pragma unroll
        for (int m = 1; m < 16; m <<= 1) {
            sN += __shfl_xor(sN, m); ssN += __shfl_xor(ssN, m);
            sL += __shfl_xor(sL, m); ssL += __shfl_xor(ssL, m);
        }
        float meanN = sN * (1.f / 128.f);
        float rstdN = rsqrtf(ssN * (1.f / 128.f) - meanN * meanN + 1e-6f);
        float meanL = sL * (1.f / 128.f);
        float rstdL = rsqrtf(ssL * (1.f / 128.f) - meanL * meanL + 1e-6f);

        // done rows: out = relu(LN(F_input) + LN(local)); nd rows: raw conv
        if (p < N_PTS) {
            float* dp = (fl & 1) ? (loc + (size_t)p * INC) : (outp + (size_t)p * INC);
#pragma unroll
            for (int j = 0; j < 8; ++j) {
                int c = (j << 4) + l15;
                float lvj = accL[j][r];
                float nn = (fj[j] - meanN) * rstdN * s_gn[c] + s_bn[c];
                float ll = (lvj - meanL) * rstdL * s_gl[c] + s_bl[c];
                float o = nn + ll; o = o > 0.f ? o : 0.f;
                dp[c] = (fl & 1) ? lvj : o;
            }
        }
    }

    // F_input store only for needs-final rows (vectorized from LDS staging)
#pragma unroll
    for (int t = 0; t < 4; ++t) {
        int row = (t << 2) + q;
        int p = p0 + (w << 4) + row;
        if (p < N_PTS && (flg[p] & 1)) {
            bf16x8 v = *(const bf16x8*)&sb[row * 136 + l15 * 8];
            *(bf16x8*)(F_input + (size_t)p * INC + l15 * 8) = v;
        }
    }
}

// ---------------- K_pairs: 16 same-slot pairs per wave, MFMA + scatter ------
__global__ __launch_bounds__(256) void k_pairs(
        const float* __restrict__ F, const __hip_bfloat16* __restrict__ Wp,
        const int* __restrict__ cnt, const int* __restrict__ dst,
        const int* __restrict__ src, float* __restrict__ loc) {
    const int b = blockIdx.x >> 7;            // bucket 0..25 (128 blocks each)
    const int chunk = blockIdx.x & 127;
    int n = cnt[b]; if (n > CAPP) n = CAPP;
    const int wv = threadIdx.x >> 6;
    const int base = chunk * 64 + wv * 16;    // this wave's 16 pairs
    if (base >= n) return;
    const int slot = b < 13 ? b : b + 1;

    const int lane = threadIdx.x & 63;
    const int q = lane >> 4, l15 = lane & 15;
    const int* srcb = src + b * CAPP;
    const int* dstb = dst + b * CAPP;

    int mrow = (base + l15 < n) ? srcb[base + l15] : 0;   // A row per l15
    const bf16x8* Bp = (const bf16x8*)Wp + (size_t)slot * 2048;

    f32x4 acc[8];
#pragma unroll
    for (int j = 0; j < 8; ++j) acc[j] = (f32x4){0.f, 0.f, 0.f, 0.f};

#pragma unroll
    for (int ks = 0; ks < 4; ++ks) {
        bf16x8 a = ld_cvt8(F + (size_t)mrow * INC + ks * 32 + q * 8);
#pragma unroll
        for (int j = 0; j < 8; ++j)
            acc[j] = __builtin_amdgcn_mfma_f32_16x16x32_bf16(a, Bp[(ks * 8 + j) * 64 + lane], acc[j], 0, 0, 0);
    }

#pragma unroll 1
    for (int m = 0; m < 16; ++m) {
        int ri = base + m;
        if (ri >= n) break;
        int d = dstb[ri];
        if (q == (m >> 2)) {
            float* lp = loc + (size_t)d * INC + l15;
            int r = m & 3;
#pragma unroll
            for (int j = 0; j < 8; ++j) atomicAdd(lp + (j << 4), acc[j][r]);
        }
    }
}

// ---------------- K_final: sparse pass; vox via cellmate GATHER -------------
// At S=2 the members of a coarse 2x2x2 cell differ by <=1 per axis, so every
// cellmate of p sits in p's 27-neighborhood at offsets dx in {0, ox} where
// ox = (x&1) ? -1 : +1 (same for y,z). vox = mean over existing cellmates of
// [F_input*cos, F_input*sin, F_input*pos] -- no aux array, no atomics.
__global__ __launch_bounds__(256) void k_final(
        const __hip_bfloat16* __restrict__ F_input, const float* __restrict__ loc,
        const int* __restrict__ nbr_idx, const int* __restrict__ coords,
        const float* __restrict__ counts_v,
        const float* __restrict__ w_pos, const float* __restrict__ alpha,
        const float* __restrict__ g_local, const float* __restrict__ b_local,
        const float* __restrict__ g_norm, const float* __restrict__ b_norm,
        const int* __restrict__ cnt, const int* __restrict__ ndl,
        float* __restrict__ out) {
    const int tid = threadIdx.x, g = tid >> 4, l15 = tid & 15;
    const int c0 = l15 * 8;
    const int nd = cnt[26];
    if (blockIdx.x * 128 >= nd) return;

    float wpv[24], pa[8], gl[8], bl[8], gn[8], bn[8];
#pragma unroll
    for (int t = 0; t < 6; ++t) ((float4*)wpv)[t] = ((const float4*)(w_pos + c0 * 3))[t];
#pragma unroll
    for (int t = 0; t < 2; ++t) {
        ((float4*)pa)[t] = ((const float4*)(alpha   + c0))[t];
        ((float4*)gl)[t] = ((const float4*)(g_local + c0))[t];
        ((float4*)bl)[t] = ((const float4*)(b_local + c0))[t];
        ((float4*)gn)[t] = ((const float4*)(g_norm  + c0))[t];
        ((float4*)bn)[t] = ((const float4*)(b_norm  + c0))[t];
    }

    for (int base = blockIdx.x * 128; base < nd; base += gridDim.x * 128) {
#pragma unroll 1
        for (int t = 0; t < 8; ++t) {
            int idx = base + t * 16 + g;
            if (idx >= nd) continue;
            int p = ndl[idx];

            float lv[8], s = 0.f, ss = 0.f;
            ((float4*)lv)[0] = *(const float4*)(loc + (size_t)p * INC + c0);
            ((float4*)lv)[1] = *(const float4*)(loc + (size_t)p * INC + c0 + 4);
#pragma unroll
            for (int j = 0; j < 8; ++j) { s += lv[j]; ss += lv[j] * lv[j]; }
#pragma unroll
            for (int m = 1; m < 16; m <<= 1) { s += __shfl_xor(s, m); ss += __shfl_xor(ss, m); }
            float meanL = s * (1.f / 128.f);
            float rstdL = rsqrtf(ss * (1.f / 128.f) - meanL * meanL + 1e-6f);

            float cv = counts_v[p];
            bool multi = cv > 1.5f;
            int ix = coords[p * 3 + 0], iy = coords[p * 3 + 1], iz = coords[p * 3 + 2];
            float cx = (float)ix, cy = (float)iy, cz = (float)iz;

            bf16x8 fbv = *(const bf16x8*)(F_input + (size_t)p * INC + c0);

            // own pos trig (needed in both paths)
            float psO[8], snO[8], csO[8], fO[8];
#pragma unroll
            for (int j = 0; j < 8; ++j) {
                fO[j] = __bfloat162float(((__hip_bfloat16*)&fbv)[j]);
                psO[j] = compute_pos3(wpv[j * 3], wpv[j * 3 + 1], wpv[j * 3 + 2], pa[j], cx, cy, cz);
                snO[j] = __sinf(psO[j]); csO[j] = __cosf(psO[j]);
            }

            float v0[8], v1[8], v2[8];
            if (multi) {
                float invc = 1.f / cv;
#pragma unroll
                for (int j = 0; j < 8; ++j) { v0[j] = 0.f; v1[j] = 0.f; v2[j] = 0.f; }
                int ox = (ix & 1) ? -1 : 1, oy = (iy & 1) ? -1 : 1, oz = (iz & 1) ? -1 : 1;
                const int* nb = nbr_idx + (size_t)p * NSLOT;
#pragma unroll 1
                for (int e = 0; e < 8; ++e) {
                    int dx = (e & 4) ? ox : 0, dy = (e & 2) ? oy : 0, dz = (e & 1) ? oz : 0;
                    int m;
                    if (e == 0) m = p;
                    else m = nb[(dx + 1) * 9 + (dy + 1) * 3 + (dz + 1)];
                    if (m >= N_PTS) continue;
                    bf16x8 fmv = *(const bf16x8*)(F_input + (size_t)m * INC + c0);
                    float mx = cx + (float)dx, my = cy + (float)dy, mz = cz + (float)dz;
#pragma unroll
                    for (int j = 0; j < 8; ++j) {
                        float fm = __bfloat162float(((__hip_bfloat16*)&fmv)[j]);
                        float ps = compute_pos3(wpv[j * 3], wpv[j * 3 + 1], wpv[j * 3 + 2], pa[j], mx, my, mz);
                        v0[j] += fm * __cosf(ps);
                        v1[j] += fm * __sinf(ps);
                        v2[j] += fm * ps;
                    }
                }
#pragma unroll
                for (int j = 0; j < 8; ++j) { v0[j] *= invc; v1[j] *= invc; v2[j] *= invc; }
            } else {
#pragma unroll
                for (int j = 0; j < 8; ++j) {
                    v0[j] = fO[j] * csO[j]; v1[j] = fO[j] * snO[j]; v2[j] = fO[j] * psO[j];
                }
            }

            float nv[8], s2 = 0.f, ss2 = 0.f;
#pragma unroll
            for (int j = 0; j < 8; ++j) {
                float nw = v0[j] * csO[j] + v1[j] * snO[j] + v2[j] - fO[j] * psO[j];
                nv[j] = nw; s2 += nw; ss2 += nw * nw;
            }
#pragma unroll
            for (int m = 1; m < 16; m <<= 1) { s2 += __shfl_xor(s2, m); ss2 += __shfl_xor(ss2, m); }
            float meanN = s2 * (1.f / 128.f);
            float rstdN = rsqrtf(ss2 * (1.f / 128.f) - meanN * meanN + 1e-6f);
            float ov[8];
#pragma unroll
            for (int j = 0; j < 8; ++j) {
                float nn = (nv[j] - meanN) * rstdN * gn[j] + bn[j];
                float ll = (lv[j] - meanL) * rstdL * gl[j] + bl[j];
                float o = nn + ll;
                ov[j] = o > 0.f ? o : 0.f;
            }
            float4* op = (float4*)(out + (size_t)p * INC + c0);
            op[0] = ((float4*)ov)[0];
            op[1] = ((float4*)ov)[1];
        }
    }
}

// ---------------- host launcher ---------------------------------------------
extern "C" void kernel_launch(void* const* d_in, const int* in_sizes, int n_in,
                              void* d_out, int out_size, void* d_ws, size_t ws_size,
                              hipStream_t stream) {
    (void)in_sizes; (void)n_in; (void)out_size; (void)ws_size;
    const float* F        = (const float*)d_in[0];
    const int*   coords   = (const int*)d_in[1];
    const int*   nbr      = (const int*)d_in[2];
    const float* counts_v = (const float*)d_in[4];
    const float* alpha    = (const float*)d_in[6];
    const float* w_pos    = (const float*)d_in[7];
    const float* w_pre    = (const float*)d_in[8];
    const float* g_pre    = (const float*)d_in[9];
    const float* b_pre    = (const float*)d_in[10];
    const float* w_conv   = (const float*)d_in[11];
    const float* g_local  = (const float*)d_in[12];
    const float* b_local  = (const float*)d_in[13];
    const float* g_norm   = (const float*)d_in[14];
    const float* b_norm   = (const float*)d_in[15];
    float* out = (float*)d_out;

    char* ws = (char*)d_ws;
    __hip_bfloat16* Wp      = (__hip_bfloat16*)(ws + OFF_WP);
    __hip_bfloat16* Wpre    = (__hip_bfloat16*)(ws + OFF_WPRE);
    __hip_bfloat16* F_input = (__hip_bfloat16*)(ws + OFF_FIN);
    float*          loc     = (float*)(ws + OFF_LOC);
    int*            cnt     = (int*)(ws + OFF_CNT);
    int*            dstb    = (int*)(ws + OFF_DST);
    int*            srcb    = (int*)(ws + OFF_SRC);
    unsigned char*  flg     = (unsigned char*)(ws + OFF_FLG);
    int*            ndl     = (int*)(ws + OFF_NDL);

    const int mt64 = (N_PTS + 63) / 64;           // 1563
    hipMemsetAsync(cnt, 0, SZ_CNT, stream);
    k_front<<<PREP_BLOCKS + SCAN_BLOCKS, 256, 0, stream>>>(
        w_pre, w_conv, Wp, Wpre, nbr, counts_v, cnt, dstb, srcb, flg, ndl);
    k_gemm<<<mt64, 256, 0, stream>>>(F, Wpre, Wp, flg,
                                     g_pre, b_pre, g_local, b_local,
                                     g_norm, b_norm, F_input, loc, out);
    k_pairs<<<26 * 128, 256, 0, stream>>>(F, Wp, cnt, dstb, srcb, loc);
    k_final<<<256, 256, 0, stream>>>(F_input, loc, nbr, coords, counts_v,
                                     w_pos, alpha, g_local, b_local, g_norm, b_norm,
                                     cnt, ndl, out);
}

// Round 6
// 257.209 us; speedup vs baseline: 1.2284x; 1.0106x over previous
//
#include <hip/hip_runtime.h>
#include <hip/hip_bf16.h>
#include <stdint.h>

#define N_PTS 100000
#define INC 128
#define NSLOT 27
#define CAPP 8192                 // pairs per slot-bucket (expected ~620)
#define SCAP 64                   // LDS staging cap per slot per block

typedef float f32x4 __attribute__((ext_vector_type(4)));
typedef short bf16x8 __attribute__((ext_vector_type(8)));

// ---------------- workspace layout --------------------------------------
static const size_t OFF_WP   = 0;                                        // 27 slots frag-packed bf16
static const size_t SZ_WP    = (size_t)NSLOT * INC * INC * 2;
static const size_t OFF_WPRE = (OFF_WP + SZ_WP + 255) & ~(size_t)255;    // w_pre frag-packed bf16
static const size_t SZ_WPRE  = (size_t)INC * INC * 2;
static const size_t OFF_FIN  = (OFF_WPRE + SZ_WPRE + 255) & ~(size_t)255; // F_input bf16
static const size_t SZ_FIN   = (size_t)N_PTS * INC * 2;
static const size_t OFF_LOC  = (OFF_FIN + SZ_FIN + 255) & ~(size_t)255;   // local accum f32
static const size_t SZ_LOC   = (size_t)N_PTS * INC * 4;
static const size_t OFF_CNT  = (OFF_LOC + SZ_LOC + 255) & ~(size_t)255;   // 26 bucket counters + [26]=ndl count
static const size_t SZ_CNT   = 128;
static const size_t OFF_DST  = (OFF_CNT + SZ_CNT + 255) & ~(size_t)255;
static const size_t SZ_DST   = (size_t)26 * CAPP * 4;
static const size_t OFF_SRC  = (OFF_DST + SZ_DST + 255) & ~(size_t)255;
static const size_t SZ_SRC   = (size_t)26 * CAPP * 4;
static const size_t OFF_FLG  = (OFF_SRC + SZ_SRC + 255) & ~(size_t)255;   // per-point flags u8
static const size_t SZ_FLG   = (size_t)N_PTS;
static const size_t OFF_NDL  = (OFF_FLG + SZ_FLG + 255) & ~(size_t)255;   // needs-final point list
static const size_t SZ_NDL   = (size_t)N_PTS * 4;                          // total ~80 MB

#define PREP_BLOCKS 1792
#define SCAN_BLOCKS 391

__device__ __forceinline__ float compute_pos3(float w0, float w1, float w2, float a,
                                              float cx, float cy, float cz) {
    return (cx * w0 + cy * w1 + cz * w2) * a;
}

// load 8 consecutive f32 and round to a bf16x8 MFMA fragment
__device__ __forceinline__ bf16x8 ld_cvt8(const float* __restrict__ p) {
    const float4 u = *(const float4*)p;
    const float4 v = *(const float4*)(p + 4);
    bf16x8 r;
    __hip_bfloat16* h = (__hip_bfloat16*)&r;
    h[0] = __float2bfloat16(u.x); h[1] = __float2bfloat16(u.y);
    h[2] = __float2bfloat16(u.z); h[3] = __float2bfloat16(u.w);
    h[4] = __float2bfloat16(v.x); h[5] = __float2bfloat16(v.y);
    h[6] = __float2bfloat16(v.z); h[7] = __float2bfloat16(v.w);
    return r;
}

// ---------------- K_front: weight pack (blocks < PREP_BLOCKS) + scan --------
__global__ __launch_bounds__(256) void k_front(
        const float* __restrict__ w_pre, const float* __restrict__ w_conv,
        __hip_bfloat16* __restrict__ Wp, __hip_bfloat16* __restrict__ Wpre,
        const int* __restrict__ nbr_idx, const float* __restrict__ counts_v,
        int* __restrict__ cnt, int* __restrict__ dst, int* __restrict__ src,
        unsigned char* __restrict__ flg, int* __restrict__ ndl) {
    __shared__ int s_cnt[26], s_base[26];
    __shared__ int s_dst[26][SCAP], s_src[26][SCAP];

    const int tid = threadIdx.x;

    if (blockIdx.x < PREP_BLOCKS) {
        // ---- prep part: pack weights (coalesced source reads) ----
        int i = blockIdx.x * 256 + tid;
        if (i < 16384) {                        // w_pre: B[n=d][k=c] = w_pre[d*128+c]
            int d = i >> 7, c = i & 127;
            int j = ((c >> 5) << 12) | ((d >> 4) << 9)
                  | (((((c >> 3) & 3) << 4) + (d & 15)) << 3) | (c & 7);
            Wpre[j] = __float2bfloat16(w_pre[i]);
        } else if (i < 16384 + NSLOT * 16384) { // w_conv: B[n=d][k=c] = w_conv[slot][c][d]
            int t = i - 16384;
            int slot = t >> 14, rem = t & 16383;
            int c = rem >> 7, d = rem & 127;
            int j = (slot << 14) | ((c >> 5) << 12) | ((d >> 4) << 9)
                  | (((((c >> 3) & 3) << 4) + (d & 15)) << 3) | (c & 7);
            Wp[j] = __float2bfloat16(w_conv[t]);
        }
        return;
    }

    // ---- scan part: pair compaction + flags + needs-final list ----
    const int lane = tid & 63;
    const int p = (blockIdx.x - PREP_BLOCKS) * 256 + tid;
    const bool vp = p < N_PTS;

    if (tid < 26) s_cnt[tid] = 0;
    __syncthreads();

    float cv = vp ? counts_v[p] : 0.f;
    bool multi = cv > 1.5f;

    const int* nb = nbr_idx + (size_t)p * NSLOT;
    bool hn = false;
#pragma unroll                               // batch all 26 neighbor loads
    for (int k = 0; k < NSLOT; ++k) {
        if (k == 13) continue;               // self handled densely
        int m = vp ? nb[k] : N_PTS;
        if (m < N_PTS) {
            hn = true;
            int b = k < 13 ? k : k - 1;      // 0..25
            int li = atomicAdd(&s_cnt[b], 1);
            if (li < SCAP) { s_dst[b][li] = p; s_src[b][li] = m; }
            else {
                int gi = atomicAdd(&cnt[b], 1);
                if (gi < CAPP) { dst[b * CAPP + gi] = p; src[b * CAPP + gi] = m; }
            }
        }
    }

    // flags: bit0 = needs k_final (multi or has occupied neighbor)
    bool nd = vp && (hn || multi);
    if (vp) flg[p] = (unsigned char)(nd ? 1 : 0);
    unsigned long long mb = __ballot(nd);
    int basew = 0;
    if (lane == 0 && mb) basew = atomicAdd(&cnt[26], __popcll(mb));
    basew = __shfl(basew, 0);
    if (nd) ndl[basew + __popcll(mb & ((1ull << lane) - 1))] = p;

    __syncthreads();

    if (tid < 26) {
        int n = s_cnt[tid]; if (n > SCAP) n = SCAP;
        s_base[tid] = n > 0 ? atomicAdd(&cnt[tid], n) : 0;
        s_cnt[tid] = n;
    }
    __syncthreads();

    for (int b = tid >> 3; b < 26; b += 32) {
        int n = s_cnt[b], base = s_base[b];
        for (int e = tid & 7; e < n; e += 8) {
            int gi = base + e;
            if (gi < CAPP) { dst[b * CAPP + gi] = s_dst[b][e]; src[b * CAPP + gi] = s_src[b][e]; }
        }
    }
}

// ---------------- K_gemm: merged pre_mix + self-conv GEMM, fused final ------
// 16 rows/wave, 6250 waves. Phase-split software pipeline: issue 8 bL loads,
// run 8 accP MFMAs (on bP issued a full phase earlier), issue next 8 bP loads,
// run 8 accL MFMAs. 16 B-frags (64 VGPR) in flight -> MLP instead of JIT loads
// (R5: VGPR 64, 95% stall). launch_bounds(256,3) gives allocator headroom
// (~95 VGPR + 64 AGPR = 3 waves/SIMD; LDS 20.5 KB permits it).
// Flags prefetched at entry -> epilogue has no dependent global loads.
__global__ __launch_bounds__(256, 3) void k_gemm(
        const float* __restrict__ F, const __hip_bfloat16* __restrict__ Wpre,
        const __hip_bfloat16* __restrict__ Wp, const unsigned char* __restrict__ flg,
        const float* __restrict__ g_pre, const float* __restrict__ b_pre,
        const float* __restrict__ g_local, const float* __restrict__ b_local,
        const float* __restrict__ g_norm, const float* __restrict__ b_norm,
        __hip_bfloat16* __restrict__ F_input, float* __restrict__ loc,
        float* __restrict__ outp) {
    __shared__ __hip_bfloat16 s_bf[4][16 * 136];   // per-wave F_input staging
    __shared__ float s_gp[INC], s_bp[INC], s_gl[INC], s_bl[INC], s_gn[INC], s_bn[INC];

    const int tid = threadIdx.x, w = tid >> 6, lane = tid & 63;
    const int q = lane >> 4, l15 = lane & 15;
    const int p0 = blockIdx.x * 64;

    if (tid < INC) {
        s_gp[tid] = g_pre[tid];   s_bp[tid] = b_pre[tid];
        s_gl[tid] = g_local[tid]; s_bl[tid] = b_local[tid];
        s_gn[tid] = g_norm[tid];  s_bn[tid] = b_norm[tid];
    }
    __syncthreads();

    int grow = p0 + (w << 4) + l15;
    if (grow >= N_PTS) grow = N_PTS - 1;      // clamp; stores guarded

    const float* A = F + (size_t)grow * INC + q * 8;

    // ---- prefetched flags: epilogue rows (q*4+r) and store rows (t*4+q) ----
    unsigned int fe = *(const unsigned int*)(flg + p0 + (w << 4) + (q << 2));
    unsigned char fs0 = flg[p0 + (w << 4) + q];
    unsigned char fs1 = flg[p0 + (w << 4) + 4 + q];
    unsigned char fs2 = flg[p0 + (w << 4) + 8 + q];
    unsigned char fs3 = flg[p0 + (w << 4) + 12 + q];

    // A fragments: load + convert ONCE, shared by both GEMMs
    bf16x8 a[4];
#pragma unroll
    for (int ks = 0; ks < 4; ++ks) a[ks] = ld_cvt8(A + ks * 32);

    // ---- phase-split pipelined MFMA loop ----
    const bf16x8* BP = (const bf16x8*)Wpre;
    const bf16x8* BL = (const bf16x8*)Wp + (size_t)13 * 2048;
    f32x4 accP[8], accL[8];
#pragma unroll
    for (int j = 0; j < 8; ++j) {
        accP[j] = (f32x4){0.f, 0.f, 0.f, 0.f};
        accL[j] = (f32x4){0.f, 0.f, 0.f, 0.f};
    }
    bf16x8 bP[8], bL[8];
#pragma unroll
    for (int j = 0; j < 8; ++j) bP[j] = BP[j * 64 + lane];          // ks=0 P loads
#pragma unroll
    for (int ks = 0; ks < 4; ++ks) {
#pragma unroll
        for (int j = 0; j < 8; ++j) bL[j] = BL[(ks * 8 + j) * 64 + lane];   // issue L(ks)
#pragma unroll
        for (int j = 0; j < 8; ++j)
            accP[j] = __builtin_amdgcn_mfma_f32_16x16x32_bf16(a[ks], bP[j], accP[j], 0, 0, 0);
        if (ks < 3) {
#pragma unroll
            for (int j = 0; j < 8; ++j) bP[j] = BP[((ks + 1) * 8 + j) * 64 + lane]; // issue P(ks+1)
        }
#pragma unroll
        for (int j = 0; j < 8; ++j)
            accL[j] = __builtin_amdgcn_mfma_f32_16x16x32_bf16(a[ks], bL[j], accL[j], 0, 0, 0);
    }

    // ---- merged epilogue per row ----
    __hip_bfloat16* sb = s_bf[w];
#pragma unroll
    for (int r = 0; r < 4; ++r) {
        int ri = (q << 2) + r;
        int p = p0 + (w << 4) + ri;
        int fl = (p < N_PTS) ? (int)((fe >> (r * 8)) & 1) : 1;

        // reduce pre_mix row stats
        float s = 0.f, ss = 0.f;
#pragma unroll
        for (int j = 0; j < 8; ++j) { float v = accP[j][r]; s += v; ss += v * v; }
#pragma unroll
        for (int m = 1; m < 16; m <<= 1) { s += __shfl_xor(s, m); ss += __shfl_xor(ss, m); }
        float mean = s * (1.f / 128.f);
        float rstd = rsqrtf(ss * (1.f / 128.f) - mean * mean + 1e-6f);

        // LN_pre -> fj (bf16-quantized, matches F_input numerics) + staging
        float fj[8], sN = 0.f, ssN = 0.f, sL = 0.f, ssL = 0.f;
#pragma unroll
        for (int j = 0; j < 8; ++j) {
            int c = (j << 4) + l15;
            float fi = (accP[j][r] - mean) * rstd * s_gp[c] + s_bp[c];
            __hip_bfloat16 fb = __float2bfloat16(fi);
            sb[ri * 136 + c] = fb;
            float f = __bfloat162float(fb);
            fj[j] = f; sN += f; ssN += f * f;
            float v = accL[j][r]; sL += v; ssL += v * v;
        }
#pragma unroll
        for (int m = 1; m < 16; m <<= 1) {
            sN += __shfl_xor(sN, m); ssN += __shfl_xor(ssN, m);
            sL += __shfl_xor(sL, m); ssL += __shfl_xor(ssL, m);
        }
        float meanN = sN * (1.f / 128.f);
        float rstdN = rsqrtf(ssN * (1.f / 128.f) - meanN * meanN + 1e-6f);
        float meanL = sL * (1.f / 128.f);
        float rstdL = rsqrtf(ssL * (1.f / 128.f) - meanL * meanL + 1e-6f);

        // done rows: out = relu(LN(F_input) + LN(local)); nd rows: raw conv
        if (p < N_PTS) {
            float* dp = fl ? (loc + (size_t)p * INC) : (outp + (size_t)p * INC);
#pragma unroll
            for (int j = 0; j < 8; ++j) {
                int c = (j << 4) + l15;
                float lvj = accL[j][r];
                float nn = (fj[j] - meanN) * rstdN * s_gn[c] + s_bn[c];
                float ll = (lvj - meanL) * rstdL * s_gl[c] + s_bl[c];
                float o = nn + ll; o = o > 0.f ? o : 0.f;
                dp[c] = fl ? lvj : o;
            }
        }
    }

    // F_input store only for needs-final rows (vectorized from LDS staging)
    {
        unsigned char fsv[4] = {fs0, fs1, fs2, fs3};
#pragma unroll
        for (int t = 0; t < 4; ++t) {
            int row = (t << 2) + q;
            int p = p0 + (w << 4) + row;
            if (p < N_PTS && (fsv[t] & 1)) {
                bf16x8 v = *(const bf16x8*)&sb[row * 136 + l15 * 8];
                *(bf16x8*)(F_input + (size_t)p * INC + l15 * 8) = v;
            }
        }
    }
}

// ---------------- K_pairs: 16 same-slot pairs per wave, MFMA + scatter ------
__global__ __launch_bounds__(256) void k_pairs(
        const float* __restrict__ F, const __hip_bfloat16* __restrict__ Wp,
        const int* __restrict__ cnt, const int* __restrict__ dst,
        const int* __restrict__ src, float* __restrict__ loc) {
    const int b = blockIdx.x >> 7;            // bucket 0..25 (128 blocks each)
    const int chunk = blockIdx.x & 127;
    int n = cnt[b]; if (n > CAPP) n = CAPP;
    const int wv = threadIdx.x >> 6;
    const int base = chunk * 64 + wv * 16;    // this wave's 16 pairs
    if (base >= n) return;
    const int slot = b < 13 ? b : b + 1;

    const int lane = threadIdx.x & 63;
    const int q = lane >> 4, l15 = lane & 15;
    const int* srcb = src + b * CAPP;
    const int* dstb = dst + b * CAPP;

    int mrow = (base + l15 < n) ? srcb[base + l15] : 0;   // A row per l15
    const bf16x8* Bp = (const bf16x8*)Wp + (size_t)slot * 2048;

    f32x4 acc[8];
#pragma unroll
    for (int j = 0; j < 8; ++j) acc[j] = (f32x4){0.f, 0.f, 0.f, 0.f};

#pragma unroll
    for (int ks = 0; ks < 4; ++ks) {
        bf16x8 a = ld_cvt8(F + (size_t)mrow * INC + ks * 32 + q * 8);
#pragma unroll
        for (int j = 0; j < 8; ++j)
            acc[j] = __builtin_amdgcn_mfma_f32_16x16x32_bf16(a, Bp[(ks * 8 + j) * 64 + lane], acc[j], 0, 0, 0);
    }

#pragma unroll 1
    for (int m = 0; m < 16; ++m) {
        int ri = base + m;
        if (ri >= n) break;
        int d = dstb[ri];
        if (q == (m >> 2)) {
            float* lp = loc + (size_t)d * INC + l15;
            int r = m & 3;
#pragma unroll
            for (int j = 0; j < 8; ++j) atomicAdd(lp + (j << 4), acc[j][r]);
        }
    }
}

// ---------------- K_final: sparse pass; vox via cellmate GATHER -------------
// At S=2 cellmates sit in p's 27-neighborhood at offsets {0,ox}x{0,oy}x{0,oz},
// ox = (x&1) ? -1 : +1. vox = mean over existing cellmates -- no aux/atomics.
__global__ __launch_bounds__(256) void k_final(
        const __hip_bfloat16* __restrict__ F_input, const float* __restrict__ loc,
        const int* __restrict__ nbr_idx, const int* __restrict__ coords,
        const float* __restrict__ counts_v,
        const float* __restrict__ w_pos, const float* __restrict__ alpha,
        const float* __restrict__ g_local, const float* __restrict__ b_local,
        const float* __restrict__ g_norm, const float* __restrict__ b_norm,
        const int* __restrict__ cnt, const int* __restrict__ ndl,
        float* __restrict__ out) {
    const int tid = threadIdx.x, g = tid >> 4, l15 = tid & 15;
    const int c0 = l15 * 8;
    const int nd = cnt[26];
    if (blockIdx.x * 128 >= nd) return;

    float wpv[24], pa[8], gl[8], bl[8], gn[8], bn[8];
#pragma unroll
    for (int t = 0; t < 6; ++t) ((float4*)wpv)[t] = ((const float4*)(w_pos + c0 * 3))[t];
#pragma unroll
    for (int t = 0; t < 2; ++t) {
        ((float4*)pa)[t] = ((const float4*)(alpha   + c0))[t];
        ((float4*)gl)[t] = ((const float4*)(g_local + c0))[t];
        ((float4*)bl)[t] = ((const float4*)(b_local + c0))[t];
        ((float4*)gn)[t] = ((const float4*)(g_norm  + c0))[t];
        ((float4*)bn)[t] = ((const float4*)(b_norm  + c0))[t];
    }

    for (int base = blockIdx.x * 128; base < nd; base += gridDim.x * 128) {
#pragma unroll 1
        for (int t = 0; t < 8; ++t) {
            int idx = base + t * 16 + g;
            if (idx >= nd) continue;
            int p = ndl[idx];

            float lv[8], s = 0.f, ss = 0.f;
            ((float4*)lv)[0] = *(const float4*)(loc + (size_t)p * INC + c0);
            ((float4*)lv)[1] = *(const float4*)(loc + (size_t)p * INC + c0 + 4);
#pragma unroll
            for (int j = 0; j < 8; ++j) { s += lv[j]; ss += lv[j] * lv[j]; }
#pragma unroll
            for (int m = 1; m < 16; m <<= 1) { s += __shfl_xor(s, m); ss += __shfl_xor(ss, m); }
            float meanL = s * (1.f / 128.f);
            float rstdL = rsqrtf(ss * (1.f / 128.f) - meanL * meanL + 1e-6f);

            float cv = counts_v[p];
            bool multi = cv > 1.5f;
            int ix = coords[p * 3 + 0], iy = coords[p * 3 + 1], iz = coords[p * 3 + 2];
            float cx = (float)ix, cy = (float)iy, cz = (float)iz;

            bf16x8 fbv = *(const bf16x8*)(F_input + (size_t)p * INC + c0);

            // own pos trig (needed in both paths)
            float psO[8], snO[8], csO[8], fO[8];
#pragma unroll
            for (int j = 0; j < 8; ++j) {
                fO[j] = __bfloat162float(((__hip_bfloat16*)&fbv)[j]);
                psO[j] = compute_pos3(wpv[j * 3], wpv[j * 3 + 1], wpv[j * 3 + 2], pa[j], cx, cy, cz);
                snO[j] = __sinf(psO[j]); csO[j] = __cosf(psO[j]);
            }

            float v0[8], v1[8], v2[8];
            if (multi) {
                float invc = 1.f / cv;
#pragma unroll
                for (int j = 0; j < 8; ++j) { v0[j] = 0.f; v1[j] = 0.f; v2[j] = 0.f; }
                int ox = (ix & 1) ? -1 : 1, oy = (iy & 1) ? -1 : 1, oz = (iz & 1) ? -1 : 1;
                const int* nb = nbr_idx + (size_t)p * NSLOT;
#pragma unroll                                   // batch the 8 cellmate gathers
                for (int e = 0; e < 8; ++e) {
                    int dx = (e & 4) ? ox : 0, dy = (e & 2) ? oy : 0, dz = (e & 1) ? oz : 0;
                    int m;
                    if (e == 0) m = p;
                    else m = nb[(dx + 1) * 9 + (dy + 1) * 3 + (dz + 1)];
                    if (m >= N_PTS) continue;
                    bf16x8 fmv = *(const bf16x8*)(F_input + (size_t)m * INC + c0);
                    float mx = cx + (float)dx, my = cy + (float)dy, mz = cz + (float)dz;
#pragma unroll
                    for (int j = 0; j < 8; ++j) {
                        float fm = __bfloat162float(((__hip_bfloat16*)&fmv)[j]);
                        float ps = compute_pos3(wpv[j * 3], wpv[j * 3 + 1], wpv[j * 3 + 2], pa[j], mx, my, mz);
                        v0[j] += fm * __cosf(ps);
                        v1[j] += fm * __sinf(ps);
                        v2[j] += fm * ps;
                    }
                }
#pragma unroll
                for (int j = 0; j < 8; ++j) { v0[j] *= invc; v1[j] *= invc; v2[j] *= invc; }
            } else {
#pragma unroll
                for (int j = 0; j < 8; ++j) {
                    v0[j] = fO[j] * csO[j]; v1[j] = fO[j] * snO[j]; v2[j] = fO[j] * psO[j];
                }
            }

            float nv[8], s2 = 0.f, ss2 = 0.f;
#pragma unroll
            for (int j = 0; j < 8; ++j) {
                float nw = v0[j] * csO[j] + v1[j] * snO[j] + v2[j] - fO[j] * psO[j];
                nv[j] = nw; s2 += nw; ss2 += nw * nw;
            }
#pragma unroll
            for (int m = 1; m < 16; m <<= 1) { s2 += __shfl_xor(s2, m); ss2 += __shfl_xor(ss2, m); }
            float meanN = s2 * (1.f / 128.f);
            float rstdN = rsqrtf(ss2 * (1.f / 128.f) - meanN * meanN + 1e-6f);
            float ov[8];
#pragma unroll
            for (int j = 0; j < 8; ++j) {
                float nn = (nv[j] - meanN) * rstdN * gn[j] + bn[j];
                float ll = (lv[j] - meanL) * rstdL * gl[j] + bl[j];
                float o = nn + ll;
                ov[j] = o > 0.f ? o : 0.f;
            }
            float4* op = (float4*)(out + (size_t)p * INC + c0);
            op[0] = ((float4*)ov)[0];
            op[1] = ((float4*)ov)[1];
        }
    }
}

// ---------------- host launcher ---------------------------------------------
extern "C" void kernel_launch(void* const* d_in, const int* in_sizes, int n_in,
                              void* d_out, int out_size, void* d_ws, size_t ws_size,
                              hipStream_t stream) {
    (void)in_sizes; (void)n_in; (void)out_size; (void)ws_size;
    const float* F        = (const float*)d_in[0];
    const int*   coords   = (const int*)d_in[1];
    const int*   nbr      = (const int*)d_in[2];
    const float* counts_v = (const float*)d_in[4];
    const float* alpha    = (const float*)d_in[6];
    const float* w_pos    = (const float*)d_in[7];
    const float* w_pre    = (const float*)d_in[8];
    const float* g_pre    = (const float*)d_in[9];
    const float* b_pre    = (const float*)d_in[10];
    const float* w_conv   = (const float*)d_in[11];
    const float* g_local  = (const float*)d_in[12];
    const float* b_local  = (const float*)d_in[13];
    const float* g_norm   = (const float*)d_in[14];
    const float* b_norm   = (const float*)d_in[15];
    float* out = (float*)d_out;

    char* ws = (char*)d_ws;
    __hip_bfloat16* Wp      = (__hip_bfloat16*)(ws + OFF_WP);
    __hip_bfloat16* Wpre    = (__hip_bfloat16*)(ws + OFF_WPRE);
    __hip_bfloat16* F_input = (__hip_bfloat16*)(ws + OFF_FIN);
    float*          loc     = (float*)(ws + OFF_LOC);
    int*            cnt     = (int*)(ws + OFF_CNT);
    int*            dstb    = (int*)(ws + OFF_DST);
    int*            srcb    = (int*)(ws + OFF_SRC);
    unsigned char*  flg     = (unsigned char*)(ws + OFF_FLG);
    int*            ndl     = (int*)(ws + OFF_NDL);

    const int mt64 = (N_PTS + 63) / 64;           // 1563
    hipMemsetAsync(cnt, 0, SZ_CNT, stream);
    k_front<<<PREP_BLOCKS + SCAN_BLOCKS, 256, 0, stream>>>(
        w_pre, w_conv, Wp, Wpre, nbr, counts_v, cnt, dstb, srcb, flg, ndl);
    k_gemm<<<mt64, 256, 0, stream>>>(F, Wpre, Wp, flg,
                                     g_pre, b_pre, g_local, b_local,
                                     g_norm, b_norm, F_input, loc, out);
    k_pairs<<<26 * 128, 256, 0, stream>>>(F, Wp, cnt, dstb, srcb, loc);
    k_final<<<256, 256, 0, stream>>>(F_input, loc, nbr, coords, counts_v,
                                     w_pos, alpha, g_local, b_local, g_norm, b_norm,
                                     cnt, ndl, out);
}

// Round 7
// 218.999 us; speedup vs baseline: 1.4427x; 1.1745x over previous
//
#include <hip/hip_runtime.h>
#include <hip/hip_bf16.h>
#include <stdint.h>

#define N_PTS 100000
#define INC 128
#define NSLOT 27
#define CAPP 8192                 // pairs per slot-bucket (expected ~620)
#define SCAP 64                   // LDS staging cap per slot per block

typedef float f32x4 __attribute__((ext_vector_type(4)));
typedef short bf16x8 __attribute__((ext_vector_type(8)));

// ---------------- workspace layout --------------------------------------
static const size_t OFF_WP   = 0;                                        // 27 slots frag-packed bf16
static const size_t SZ_WP    = (size_t)NSLOT * INC * INC * 2;
static const size_t OFF_WPRE = (OFF_WP + SZ_WP + 255) & ~(size_t)255;    // w_pre frag-packed bf16
static const size_t SZ_WPRE  = (size_t)INC * INC * 2;
static const size_t OFF_FIN  = (OFF_WPRE + SZ_WPRE + 255) & ~(size_t)255; // F_input bf16
static const size_t SZ_FIN   = (size_t)N_PTS * INC * 2;
static const size_t OFF_LOC  = (OFF_FIN + SZ_FIN + 255) & ~(size_t)255;   // self-conv f32 (by gemm)
static const size_t SZ_LOC   = (size_t)N_PTS * INC * 4;
static const size_t OFF_LOC2 = (OFF_LOC + SZ_LOC + 255) & ~(size_t)255;   // neighbor-conv f32 (atomics)
static const size_t SZ_LOC2  = (size_t)N_PTS * INC * 4;
static const size_t OFF_CNT  = (OFF_LOC2 + SZ_LOC2 + 255) & ~(size_t)255; // 26 bucket counters + [26]=ndl
static const size_t SZ_CNT   = 128;
static const size_t OFF_DST  = (OFF_CNT + SZ_CNT + 255) & ~(size_t)255;
static const size_t SZ_DST   = (size_t)26 * CAPP * 4;
static const size_t OFF_SRC  = (OFF_DST + SZ_DST + 255) & ~(size_t)255;
static const size_t SZ_SRC   = (size_t)26 * CAPP * 4;
static const size_t OFF_FLG  = (OFF_SRC + SZ_SRC + 255) & ~(size_t)255;   // per-point flags u8
static const size_t SZ_FLG   = (size_t)N_PTS;
static const size_t OFF_NDL  = (OFF_FLG + SZ_FLG + 255) & ~(size_t)255;   // needs-final point list
static const size_t SZ_NDL   = (size_t)N_PTS * 4;                          // total ~131 MB

#define PREP_BLOCKS 1792
#define SCAN_BLOCKS 391
#define MT64 1563                 // gemm-region blocks in fused kernel
#define PAIRB 256                 // pairs-region blocks in fused kernel

__device__ __forceinline__ float compute_pos3(float w0, float w1, float w2, float a,
                                              float cx, float cy, float cz) {
    return (cx * w0 + cy * w1 + cz * w2) * a;
}

// load 8 consecutive f32 and round to a bf16x8 MFMA fragment
__device__ __forceinline__ bf16x8 ld_cvt8(const float* __restrict__ p) {
    const float4 u = *(const float4*)p;
    const float4 v = *(const float4*)(p + 4);
    bf16x8 r;
    __hip_bfloat16* h = (__hip_bfloat16*)&r;
    h[0] = __float2bfloat16(u.x); h[1] = __float2bfloat16(u.y);
    h[2] = __float2bfloat16(u.z); h[3] = __float2bfloat16(u.w);
    h[4] = __float2bfloat16(v.x); h[5] = __float2bfloat16(v.y);
    h[6] = __float2bfloat16(v.z); h[7] = __float2bfloat16(v.w);
    return r;
}

// ---------------- K_front: weight pack (blocks < PREP_BLOCKS) + scan --------
__global__ __launch_bounds__(256) void k_front(
        const float* __restrict__ w_pre, const float* __restrict__ w_conv,
        __hip_bfloat16* __restrict__ Wp, __hip_bfloat16* __restrict__ Wpre,
        const int* __restrict__ nbr_idx, const float* __restrict__ counts_v,
        int* __restrict__ cnt, int* __restrict__ dst, int* __restrict__ src,
        unsigned char* __restrict__ flg, int* __restrict__ ndl,
        float* __restrict__ loc2) {
    __shared__ int s_cnt[26], s_base[26];
    __shared__ int s_dst[26][SCAP], s_src[26][SCAP];

    const int tid = threadIdx.x;

    if (blockIdx.x < PREP_BLOCKS) {
        // ---- prep part: pack weights (coalesced source reads) ----
        int i = blockIdx.x * 256 + tid;
        if (i < 16384) {                        // w_pre: B[n=d][k=c] = w_pre[d*128+c]
            int d = i >> 7, c = i & 127;
            int j = ((c >> 5) << 12) | ((d >> 4) << 9)
                  | (((((c >> 3) & 3) << 4) + (d & 15)) << 3) | (c & 7);
            Wpre[j] = __float2bfloat16(w_pre[i]);
        } else if (i < 16384 + NSLOT * 16384) { // w_conv: B[n=d][k=c] = w_conv[slot][c][d]
            int t = i - 16384;
            int slot = t >> 14, rem = t & 16383;
            int c = rem >> 7, d = rem & 127;
            int j = (slot << 14) | ((c >> 5) << 12) | ((d >> 4) << 9)
                  | (((((c >> 3) & 3) << 4) + (d & 15)) << 3) | (c & 7);
            Wp[j] = __float2bfloat16(w_conv[t]);
        }
        return;
    }

    // ---- scan part: pair compaction + flags + needs-final list ----
    const int lane = tid & 63;
    const int p = (blockIdx.x - PREP_BLOCKS) * 256 + tid;
    const bool vp = p < N_PTS;

    if (tid < 26) s_cnt[tid] = 0;
    __syncthreads();

    float cv = vp ? counts_v[p] : 0.f;
    bool multi = cv > 1.5f;

    const int* nb = nbr_idx + (size_t)p * NSLOT;
    bool hn = false;
#pragma unroll 1
    for (int k = 0; k < NSLOT; ++k) {
        if (k == 13) continue;               // self handled densely
        int m = vp ? nb[k] : N_PTS;
        if (m < N_PTS) {
            hn = true;
            int b = k < 13 ? k : k - 1;      // 0..25
            int li = atomicAdd(&s_cnt[b], 1);
            if (li < SCAP) { s_dst[b][li] = p; s_src[b][li] = m; }
            else {
                int gi = atomicAdd(&cnt[b], 1);
                if (gi < CAPP) { dst[b * CAPP + gi] = p; src[b * CAPP + gi] = m; }
            }
        }
    }

    // flags: bit0 = needs k_final (multi or has occupied neighbor)
    bool nd = vp && (hn || multi);
    if (vp) flg[p] = (unsigned char)(nd ? 1 : 0);
    if (nd) {                                // zero loc2 row (pairs atomics land here next)
        float4* row = (float4*)(loc2 + (size_t)p * INC);
#pragma unroll
        for (int i = 0; i < INC / 4; ++i) row[i] = make_float4(0.f, 0.f, 0.f, 0.f);
    }
    unsigned long long mb = __ballot(nd);
    int basew = 0;
    if (lane == 0 && mb) basew = atomicAdd(&cnt[26], __popcll(mb));
    basew = __shfl(basew, 0);
    if (nd) ndl[basew + __popcll(mb & ((1ull << lane) - 1))] = p;

    __syncthreads();

    if (tid < 26) {
        int n = s_cnt[tid]; if (n > SCAP) n = SCAP;
        s_base[tid] = n > 0 ? atomicAdd(&cnt[tid], n) : 0;
        s_cnt[tid] = n;
    }
    __syncthreads();

    for (int b = tid >> 3; b < 26; b += 32) {
        int n = s_cnt[b], base = s_base[b];
        for (int e = tid & 7; e < n; e += 8) {
            int gi = base + e;
            if (gi < CAPP) { dst[b * CAPP + gi] = s_dst[b][e]; src[b * CAPP + gi] = s_src[b][e]; }
        }
    }
}

// ---------------- K_main: FUSED gemm-region + pairs-region ------------------
// blocks [0, MT64): merged pre_mix + self-conv GEMM with fused final (R6 code).
// blocks [MT64, MT64+PAIRB): neighbor pairs. Independent of gemm output
// (atomics into loc2, zeroed by k_front) -> co-scheduled, pairs latency hides
// under gemm compute. Dense wave->pair mapping via per-block bucket prefix;
// all-lane scatter (4 iters, each q-group scatters its own pair).
__global__ __launch_bounds__(256, 3) void k_main(
        const float* __restrict__ F, const __hip_bfloat16* __restrict__ Wpre,
        const __hip_bfloat16* __restrict__ Wp, const unsigned char* __restrict__ flg,
        const float* __restrict__ g_pre, const float* __restrict__ b_pre,
        const float* __restrict__ g_local, const float* __restrict__ b_local,
        const float* __restrict__ g_norm, const float* __restrict__ b_norm,
        const int* __restrict__ cnt, const int* __restrict__ dst,
        const int* __restrict__ src,
        __hip_bfloat16* __restrict__ F_input, float* __restrict__ loc,
        float* __restrict__ loc2, float* __restrict__ outp) {
    __shared__ __hip_bfloat16 s_bf[4][16 * 136];   // per-wave F_input staging (gemm region)
    __shared__ float s_gp[INC], s_bp[INC], s_gl[INC], s_bl[INC], s_gn[INC], s_bn[INC];
    __shared__ int s_wre[27], s_cntb[26];          // pairs region

    const int tid = threadIdx.x, w = tid >> 6, lane = tid & 63;
    const int q = lane >> 4, l15 = lane & 15;

    if (blockIdx.x >= MT64) {
        // ================= pairs region =================
        const int pb = blockIdx.x - MT64;
        if (tid == 0) {
            int accw = 0; s_wre[0] = 0;
            for (int b = 0; b < 26; ++b) {
                int v = cnt[b]; if (v > CAPP) v = CAPP;
                s_cntb[b] = v;
                accw += (v + 15) >> 4;
                s_wre[b + 1] = accw;
            }
        }
        __syncthreads();
        const int W = s_wre[26];
#pragma unroll 1
        for (int wvi = pb * 4 + w; wvi < W; wvi += PAIRB * 4) {
            int b = 0;
            while (wvi >= s_wre[b + 1]) ++b;       // wave-uniform, <=26 LDS reads
            int base = (wvi - s_wre[b]) << 4;
            int nB = s_cntb[b];
            int slot = b < 13 ? b : b + 1;
            const int* srcb = src + b * CAPP;
            const int* dstb = dst + b * CAPP;
            int mrow = (base + l15 < nB) ? srcb[base + l15] : 0;
            const bf16x8* Bp = (const bf16x8*)Wp + (size_t)slot * 2048;

            f32x4 acc[8];
#pragma unroll
            for (int j = 0; j < 8; ++j) acc[j] = (f32x4){0.f, 0.f, 0.f, 0.f};
#pragma unroll
            for (int ks = 0; ks < 4; ++ks) {
                bf16x8 a2 = ld_cvt8(F + (size_t)mrow * INC + ks * 32 + q * 8);
#pragma unroll
                for (int j = 0; j < 8; ++j)
                    acc[j] = __builtin_amdgcn_mfma_f32_16x16x32_bf16(
                        a2, Bp[(ks * 8 + j) * 64 + lane], acc[j], 0, 0, 0);
            }
            // all-lane scatter: q-group g handles pairs base + g*4 + r
#pragma unroll
            for (int r = 0; r < 4; ++r) {
                int m = (q << 2) + r;
                int ri = base + m;
                if (ri < nB) {
                    int d = dstb[ri];
                    float* lp = loc2 + (size_t)d * INC + l15;
#pragma unroll
                    for (int j = 0; j < 8; ++j) atomicAdd(lp + (j << 4), acc[j][r]);
                }
            }
        }
        return;
    }

    // ================= gemm region (R6 structure) =================
    const int p0 = blockIdx.x * 64;

    if (tid < INC) {
        s_gp[tid] = g_pre[tid];   s_bp[tid] = b_pre[tid];
        s_gl[tid] = g_local[tid]; s_bl[tid] = b_local[tid];
        s_gn[tid] = g_norm[tid];  s_bn[tid] = b_norm[tid];
    }
    __syncthreads();

    int grow = p0 + (w << 4) + l15;
    if (grow >= N_PTS) grow = N_PTS - 1;      // clamp; stores guarded

    const float* A = F + (size_t)grow * INC + q * 8;

    // prefetched flags: epilogue rows (q*4+r) and store rows (t*4+q)
    unsigned int fe = *(const unsigned int*)(flg + p0 + (w << 4) + (q << 2));
    unsigned char fs0 = flg[p0 + (w << 4) + q];
    unsigned char fs1 = flg[p0 + (w << 4) + 4 + q];
    unsigned char fs2 = flg[p0 + (w << 4) + 8 + q];
    unsigned char fs3 = flg[p0 + (w << 4) + 12 + q];

    bf16x8 a[4];
#pragma unroll
    for (int ks = 0; ks < 4; ++ks) a[ks] = ld_cvt8(A + ks * 32);

    // phase-split pipelined MFMA loop
    const bf16x8* BP = (const bf16x8*)Wpre;
    const bf16x8* BL = (const bf16x8*)Wp + (size_t)13 * 2048;
    f32x4 accP[8], accL[8];
#pragma unroll
    for (int j = 0; j < 8; ++j) {
        accP[j] = (f32x4){0.f, 0.f, 0.f, 0.f};
        accL[j] = (f32x4){0.f, 0.f, 0.f, 0.f};
    }
    bf16x8 bP[8], bL[8];
#pragma unroll
    for (int j = 0; j < 8; ++j) bP[j] = BP[j * 64 + lane];
#pragma unroll
    for (int ks = 0; ks < 4; ++ks) {
#pragma unroll
        for (int j = 0; j < 8; ++j) bL[j] = BL[(ks * 8 + j) * 64 + lane];
#pragma unroll
        for (int j = 0; j < 8; ++j)
            accP[j] = __builtin_amdgcn_mfma_f32_16x16x32_bf16(a[ks], bP[j], accP[j], 0, 0, 0);
        if (ks < 3) {
#pragma unroll
            for (int j = 0; j < 8; ++j) bP[j] = BP[((ks + 1) * 8 + j) * 64 + lane];
        }
#pragma unroll
        for (int j = 0; j < 8; ++j)
            accL[j] = __builtin_amdgcn_mfma_f32_16x16x32_bf16(a[ks], bL[j], accL[j], 0, 0, 0);
    }

    // merged epilogue per row
    __hip_bfloat16* sb = s_bf[w];
#pragma unroll
    for (int r = 0; r < 4; ++r) {
        int ri = (q << 2) + r;
        int p = p0 + (w << 4) + ri;
        int fl = (p < N_PTS) ? (int)((fe >> (r * 8)) & 1) : 1;

        float s = 0.f, ss = 0.f;
#pragma unroll
        for (int j = 0; j < 8; ++j) { float v = accP[j][r]; s += v; ss += v * v; }
#pragma unroll
        for (int m = 1; m < 16; m <<= 1) { s += __shfl_xor(s, m); ss += __shfl_xor(ss, m); }
        float mean = s * (1.f / 128.f);
        float rstd = rsqrtf(ss * (1.f / 128.f) - mean * mean + 1e-6f);

        float fj[8], sN = 0.f, ssN = 0.f, sL = 0.f, ssL = 0.f;
#pragma unroll
        for (int j = 0; j < 8; ++j) {
            int c = (j << 4) + l15;
            float fi = (accP[j][r] - mean) * rstd * s_gp[c] + s_bp[c];
            __hip_bfloat16 fb = __float2bfloat16(fi);
            sb[ri * 136 + c] = fb;
            float f = __bfloat162float(fb);
            fj[j] = f; sN += f; ssN += f * f;
            float v = accL[j][r]; sL += v; ssL += v * v;
        }
#pragma unroll
        for (int m = 1; m < 16; m <<= 1) {
            sN += __shfl_xor(sN, m); ssN += __shfl_xor(ssN, m);
            sL += __shfl_xor(sL, m); ssL += __shfl_xor(ssL, m);
        }
        float meanN = sN * (1.f / 128.f);
        float rstdN = rsqrtf(ssN * (1.f / 128.f) - meanN * meanN + 1e-6f);
        float meanL = sL * (1.f / 128.f);
        float rstdL = rsqrtf(ssL * (1.f / 128.f) - meanL * meanL + 1e-6f);

        if (p < N_PTS) {
            float* dp = fl ? (loc + (size_t)p * INC) : (outp + (size_t)p * INC);
#pragma unroll
            for (int j = 0; j < 8; ++j) {
                int c = (j << 4) + l15;
                float lvj = accL[j][r];
                float nn = (fj[j] - meanN) * rstdN * s_gn[c] + s_bn[c];
                float ll = (lvj - meanL) * rstdL * s_gl[c] + s_bl[c];
                float o = nn + ll; o = o > 0.f ? o : 0.f;
                dp[c] = fl ? lvj : o;
            }
        }
    }

    // F_input store only for needs-final rows
    {
        unsigned char fsv[4] = {fs0, fs1, fs2, fs3};
#pragma unroll
        for (int t = 0; t < 4; ++t) {
            int row = (t << 2) + q;
            int p = p0 + (w << 4) + row;
            if (p < N_PTS && (fsv[t] & 1)) {
                bf16x8 v = *(const bf16x8*)&sb[row * 136 + l15 * 8];
                *(bf16x8*)(F_input + (size_t)p * INC + l15 * 8) = v;
            }
        }
    }
}

// ---------------- K_final: sparse pass; vox via cellmate GATHER -------------
// local = loc (self, from gemm) + loc2 (neighbors, from pairs atomics).
// 2-phase batched gather: 8 indices first, then 8 rows (MLP), masked math.
__global__ __launch_bounds__(256) void k_final(
        const __hip_bfloat16* __restrict__ F_input, const float* __restrict__ loc,
        const float* __restrict__ loc2,
        const int* __restrict__ nbr_idx, const int* __restrict__ coords,
        const float* __restrict__ counts_v,
        const float* __restrict__ w_pos, const float* __restrict__ alpha,
        const float* __restrict__ g_local, const float* __restrict__ b_local,
        const float* __restrict__ g_norm, const float* __restrict__ b_norm,
        const int* __restrict__ cnt, const int* __restrict__ ndl,
        float* __restrict__ out) {
    const int tid = threadIdx.x, g = tid >> 4, l15 = tid & 15;
    const int c0 = l15 * 8;
    const int nd = cnt[26];
    if (blockIdx.x * 64 >= nd) return;

    float wpv[24], pa[8], gl[8], bl[8], gn[8], bn[8];
#pragma unroll
    for (int t = 0; t < 6; ++t) ((float4*)wpv)[t] = ((const float4*)(w_pos + c0 * 3))[t];
#pragma unroll
    for (int t = 0; t < 2; ++t) {
        ((float4*)pa)[t] = ((const float4*)(alpha   + c0))[t];
        ((float4*)gl)[t] = ((const float4*)(g_local + c0))[t];
        ((float4*)bl)[t] = ((const float4*)(b_local + c0))[t];
        ((float4*)gn)[t] = ((const float4*)(g_norm  + c0))[t];
        ((float4*)bn)[t] = ((const float4*)(b_norm  + c0))[t];
    }

    for (int base = blockIdx.x * 64; base < nd; base += gridDim.x * 64) {
#pragma unroll 1
        for (int t = 0; t < 4; ++t) {
            int idx = base + t * 16 + g;
            if (idx >= nd) continue;
            int p = ndl[idx];

            float lv[8], s = 0.f, ss = 0.f;
            float4 la0 = *(const float4*)(loc  + (size_t)p * INC + c0);
            float4 la1 = *(const float4*)(loc  + (size_t)p * INC + c0 + 4);
            float4 lb0 = *(const float4*)(loc2 + (size_t)p * INC + c0);
            float4 lb1 = *(const float4*)(loc2 + (size_t)p * INC + c0 + 4);
            lv[0] = la0.x + lb0.x; lv[1] = la0.y + lb0.y;
            lv[2] = la0.z + lb0.z; lv[3] = la0.w + lb0.w;
            lv[4] = la1.x + lb1.x; lv[5] = la1.y + lb1.y;
            lv[6] = la1.z + lb1.z; lv[7] = la1.w + lb1.w;
#pragma unroll
            for (int j = 0; j < 8; ++j) { s += lv[j]; ss += lv[j] * lv[j]; }
#pragma unroll
            for (int m = 1; m < 16; m <<= 1) { s += __shfl_xor(s, m); ss += __shfl_xor(ss, m); }
            float meanL = s * (1.f / 128.f);
            float rstdL = rsqrtf(ss * (1.f / 128.f) - meanL * meanL + 1e-6f);

            float cv = counts_v[p];
            bool multi = cv > 1.5f;
            int ix = coords[p * 3 + 0], iy = coords[p * 3 + 1], iz = coords[p * 3 + 2];
            float cx = (float)ix, cy = (float)iy, cz = (float)iz;

            bf16x8 fbv = *(const bf16x8*)(F_input + (size_t)p * INC + c0);

            float psO[8], snO[8], csO[8], fO[8];
#pragma unroll
            for (int j = 0; j < 8; ++j) {
                fO[j] = __bfloat162float(((__hip_bfloat16*)&fbv)[j]);
                psO[j] = compute_pos3(wpv[j * 3], wpv[j * 3 + 1], wpv[j * 3 + 2], pa[j], cx, cy, cz);
                snO[j] = __sinf(psO[j]); csO[j] = __cosf(psO[j]);
            }

            float v0[8], v1[8], v2[8];
            if (multi) {
                float invc = 1.f / cv;
                int ox = (ix & 1) ? -1 : 1, oy = (iy & 1) ? -1 : 1, oz = (iz & 1) ? -1 : 1;
                const int* nb = nbr_idx + (size_t)p * NSLOT;
                // phase 1: all 8 cellmate indices + all 8 rows in flight
                float wt8[8], mx8[8], my8[8], mz8[8];
                bf16x8 fmv8[8];
#pragma unroll
                for (int e = 0; e < 8; ++e) {
                    int dx = (e & 4) ? ox : 0, dy = (e & 2) ? oy : 0, dz = (e & 1) ? oz : 0;
                    int m = (e == 0) ? p : nb[(dx + 1) * 9 + (dy + 1) * 3 + (dz + 1)];
                    bool ok = m < N_PTS;
                    wt8[e] = ok ? 1.f : 0.f;
                    int mc = ok ? m : p;
                    fmv8[e] = *(const bf16x8*)(F_input + (size_t)mc * INC + c0);
                    mx8[e] = cx + (float)dx; my8[e] = cy + (float)dy; mz8[e] = cz + (float)dz;
                }
#pragma unroll
                for (int j = 0; j < 8; ++j) { v0[j] = 0.f; v1[j] = 0.f; v2[j] = 0.f; }
                // phase 2: masked accumulation (wt=0 contributes exactly 0)
#pragma unroll
                for (int e = 0; e < 8; ++e) {
#pragma unroll
                    for (int j = 0; j < 8; ++j) {
                        float fm = wt8[e] * __bfloat162float(((__hip_bfloat16*)&fmv8[e])[j]);
                        float ps = compute_pos3(wpv[j * 3], wpv[j * 3 + 1], wpv[j * 3 + 2], pa[j],
                                                mx8[e], my8[e], mz8[e]);
                        v0[j] += fm * __cosf(ps);
                        v1[j] += fm * __sinf(ps);
                        v2[j] += fm * ps;
                    }
                }
#pragma unroll
                for (int j = 0; j < 8; ++j) { v0[j] *= invc; v1[j] *= invc; v2[j] *= invc; }
            } else {
#pragma unroll
                for (int j = 0; j < 8; ++j) {
                    v0[j] = fO[j] * csO[j]; v1[j] = fO[j] * snO[j]; v2[j] = fO[j] * psO[j];
                }
            }

            float nv[8], s2 = 0.f, ss2 = 0.f;
#pragma unroll
            for (int j = 0; j < 8; ++j) {
                float nw = v0[j] * csO[j] + v1[j] * snO[j] + v2[j] - fO[j] * psO[j];
                nv[j] = nw; s2 += nw; ss2 += nw * nw;
            }
#pragma unroll
            for (int m = 1; m < 16; m <<= 1) { s2 += __shfl_xor(s2, m); ss2 += __shfl_xor(ss2, m); }
            float meanN = s2 * (1.f / 128.f);
            float rstdN = rsqrtf(ss2 * (1.f / 128.f) - meanN * meanN + 1e-6f);
            float ov[8];
#pragma unroll
            for (int j = 0; j < 8; ++j) {
                float nn = (nv[j] - meanN) * rstdN * gn[j] + bn[j];
                float ll = (lv[j] - meanL) * rstdL * gl[j] + bl[j];
                float o = nn + ll;
                ov[j] = o > 0.f ? o : 0.f;
            }
            float4* op = (float4*)(out + (size_t)p * INC + c0);
            op[0] = ((float4*)ov)[0];
            op[1] = ((float4*)ov)[1];
        }
    }
}

// ---------------- host launcher ---------------------------------------------
extern "C" void kernel_launch(void* const* d_in, const int* in_sizes, int n_in,
                              void* d_out, int out_size, void* d_ws, size_t ws_size,
                              hipStream_t stream) {
    (void)in_sizes; (void)n_in; (void)out_size; (void)ws_size;
    const float* F        = (const float*)d_in[0];
    const int*   coords   = (const int*)d_in[1];
    const int*   nbr      = (const int*)d_in[2];
    const float* counts_v = (const float*)d_in[4];
    const float* alpha    = (const float*)d_in[6];
    const float* w_pos    = (const float*)d_in[7];
    const float* w_pre    = (const float*)d_in[8];
    const float* g_pre    = (const float*)d_in[9];
    const float* b_pre    = (const float*)d_in[10];
    const float* w_conv   = (const float*)d_in[11];
    const float* g_local  = (const float*)d_in[12];
    const float* b_local  = (const float*)d_in[13];
    const float* g_norm   = (const float*)d_in[14];
    const float* b_norm   = (const float*)d_in[15];
    float* out = (float*)d_out;

    char* ws = (char*)d_ws;
    __hip_bfloat16* Wp      = (__hip_bfloat16*)(ws + OFF_WP);
    __hip_bfloat16* Wpre    = (__hip_bfloat16*)(ws + OFF_WPRE);
    __hip_bfloat16* F_input = (__hip_bfloat16*)(ws + OFF_FIN);
    float*          loc     = (float*)(ws + OFF_LOC);
    float*          loc2    = (float*)(ws + OFF_LOC2);
    int*            cnt     = (int*)(ws + OFF_CNT);
    int*            dstb    = (int*)(ws + OFF_DST);
    int*            srcb    = (int*)(ws + OFF_SRC);
    unsigned char*  flg     = (unsigned char*)(ws + OFF_FLG);
    int*            ndl     = (int*)(ws + OFF_NDL);

    hipMemsetAsync(cnt, 0, SZ_CNT, stream);
    k_front<<<PREP_BLOCKS + SCAN_BLOCKS, 256, 0, stream>>>(
        w_pre, w_conv, Wp, Wpre, nbr, counts_v, cnt, dstb, srcb, flg, ndl, loc2);
    k_main<<<MT64 + PAIRB, 256, 0, stream>>>(
        F, Wpre, Wp, flg, g_pre, b_pre, g_local, b_local, g_norm, b_norm,
        cnt, dstb, srcb, F_input, loc, loc2, out);
    k_final<<<512, 256, 0, stream>>>(F_input, loc, loc2, nbr, coords, counts_v,
                                     w_pos, alpha, g_local, b_local, g_norm, b_norm,
                                     cnt, ndl, out);
}